// Round 5
// baseline (640.927 us; speedup 1.0000x reference)
//
#include <hip/hip_runtime.h>

#define N_NODES 51200
#define N_EDGES 819200
#define HDIM 128
#define AK 256          // GEMM K = 2*HDIM (agg | x)
#define NGRAPH 128
#define SEG 400
#define NOUT 10
#define NS 8            // CSR slices (one per XCD via blockIdx%8 heuristic)
#define CSR_M (NS * N_NODES)

typedef unsigned short ushort_t;
typedef __attribute__((ext_vector_type(8))) short bf16x8;
typedef __attribute__((ext_vector_type(16))) float f32x16;

static __device__ __forceinline__ unsigned short f2bf(float f) {
    unsigned int u = __float_as_uint(f);
    unsigned int r = (u + 0x7fffu + ((u >> 16) & 1u)) >> 16;  // RNE
    return (unsigned short)r;
}
static __device__ __forceinline__ float bf2f(unsigned short h) {
    return __uint_as_float(((unsigned int)h) << 16);
}

// ---------------- CSR build (8-way sliced by blockIdx%8 for XCD write locality) ----

__global__ void k_count(const int* __restrict__ dst, int* __restrict__ counts) {
    int e = blockIdx.x * 256 + threadIdx.x;
    int s = blockIdx.x & 7;
    atomicAdd(&counts[s * N_NODES + dst[e]], 1);
}

// block = 256 threads, 4 items/thread -> 1024 elements/block; grid = CSR_M/1024 = 400
__global__ void k_scan_block(const int* __restrict__ counts,
                             int* __restrict__ partial,
                             int* __restrict__ blocksums) {
    __shared__ int tsum[256];
    int tid = threadIdx.x;
    int base = blockIdx.x * 1024 + tid * 4;
    int4 c = *(const int4*)(counts + base);
    int s1 = c.x, s2 = s1 + c.y, s3 = s2 + c.z, s4 = s3 + c.w;
    tsum[tid] = s4;
    __syncthreads();
    for (int off = 1; off < 256; off <<= 1) {
        int t = (tid >= off) ? tsum[tid - off] : 0;
        __syncthreads();
        tsum[tid] += t;
        __syncthreads();
    }
    int excl = tsum[tid] - s4;
    int4 o;
    o.x = excl; o.y = excl + s1; o.z = excl + s2; o.w = excl + s3;
    *(int4*)(partial + base) = o;
    if (tid == 255) blocksums[blockIdx.x] = tsum[255];
}

// single block, 512 threads, scans 400 block sums
__global__ void k_scan_top(const int* __restrict__ blocksums, int* __restrict__ blockoffs) {
    __shared__ int s[512];
    int tid = threadIdx.x;
    int v = (tid < 400) ? blocksums[tid] : 0;
    s[tid] = v;
    __syncthreads();
    for (int off = 1; off < 512; off <<= 1) {
        int t = (tid >= off) ? s[tid - off] : 0;
        __syncthreads();
        s[tid] += t;
        __syncthreads();
    }
    if (tid < 400) blockoffs[tid] = s[tid] - v;
}

__global__ void k_rowptr(const int* __restrict__ partial, const int* __restrict__ blockoffs,
                         int* __restrict__ row_ptr) {
    int i = blockIdx.x * 256 + threadIdx.x;
    if (i < CSR_M) row_ptr[i] = partial[i] + blockoffs[i >> 10];
    if (i == 0) row_ptr[CSR_M] = N_EDGES;
}

__global__ void k_fill(const int* __restrict__ src, const int* __restrict__ dst,
                       const int* __restrict__ row_ptr, int* __restrict__ cursor,
                       ushort_t* __restrict__ col) {
    int e = blockIdx.x * 256 + threadIdx.x;
    int idx = (blockIdx.x & 7) * N_NODES + dst[e];
    int pos = row_ptr[idx] + atomicAdd(&cursor[idx], 1);
    col[pos] = (ushort_t)src[e];
}

// ---------------- cast x0 -> Abuf right half (bf16) ----------------

__global__ void k_cast(const float* __restrict__ x, ushort_t* __restrict__ Abuf) {
    int idx = blockIdx.x * 256 + threadIdx.x;
    int row = idx >> 5;
    int c4 = (idx & 31) * 4;
    float4 v = *(const float4*)(x + (size_t)row * HDIM + c4);
    ushort4 h;
    h.x = f2bf(v.x); h.y = f2bf(v.y); h.z = f2bf(v.z); h.w = f2bf(v.w);
    *(ushort4*)(Abuf + (size_t)row * AK + HDIM + c4) = h;
}

// ---------------- aggregation: column-sliced for XCD L2 residency ----------------
// block -> (colgroup = blockIdx&3 [32 cols = one 64B line], node-parity = bit2)
// wave = 4 nodes x 16 lanes; each 16-lane group walks its node's 8 slice segments

__global__ __launch_bounds__(256) void k_aggregate(ushort_t* __restrict__ Abuf,
                                                   const int* __restrict__ rp,
                                                   const ushort_t* __restrict__ col) {
    int b = blockIdx.x;
    int cg = b & 3;
    int par = (b >> 2) & 1;
    int rest = b >> 3;
    int node_base = (rest * 2 + par) * 16;

    int tid = threadIdx.x;
    int wv = tid >> 6;
    int lane = tid & 63;
    int grp = lane >> 4;
    int li = lane & 15;
    int node = node_base + wv * 4 + grp;

    int beg = 0, cnt = 0;
    if (li < 8) {
        int i = li * N_NODES + node;
        beg = rp[i];
        cnt = rp[i + 1] - beg;
    }

    float a0 = 0.f, a1 = 0.f;
    const ushort_t* xsrc = Abuf + HDIM + cg * 32 + li * 2;

#pragma unroll
    for (int c = 0; c < 8; ++c) {
        int b0 = __shfl(beg, grp * 16 + c);
        int n0 = __shfl(cnt, grp * 16 + c);
        for (int e = b0; e < b0 + n0; ++e) {
            int sidx = (int)col[e];                       // same addr per group -> broadcast
            unsigned int v = *(const unsigned int*)(xsrc + (size_t)sidx * AK);
            a0 += __uint_as_float(v << 16);
            a1 += __uint_as_float(v & 0xffff0000u);
        }
    }

    unsigned int packed = (unsigned int)f2bf(a0) | ((unsigned int)f2bf(a1) << 16);
    *(unsigned int*)(Abuf + (size_t)node * AK + cg * 32 + li * 2) = packed;
}

// ---------------- weight fragment prep ----------------

__global__ void k_wfrag(const float* __restrict__ Wrel, const float* __restrict__ Wroot,
                        ushort_t* __restrict__ dstF) {
    int tid = blockIdx.x * 256 + threadIdx.x;  // 0..32767
    int j = tid & 7;
    int l = (tid >> 3) & 63;
    int s = (tid >> 9) & 15;
    int t = tid >> 13;
    int k = 16 * s + (l >> 5) * 8 + j;
    int n = 32 * t + (l & 31);
    float v = (k < HDIM) ? Wrel[(size_t)k * HDIM + n] : Wroot[(size_t)(k - HDIM) * HDIM + n];
    dstF[tid] = f2bf(v);
}

// ---------------- MFMA GEMM (layers 1-2): y = relu([agg|x] @ W + b) -------------

__global__ __launch_bounds__(64) void k_gemm_mfma(const ushort_t* __restrict__ Abuf,
                                                  const ushort_t* __restrict__ Wfrag,
                                                  const float* __restrict__ bias,
                                                  ushort_t* __restrict__ y) {
    __shared__ ushort_t sm[32][136];
    int lane = threadIdx.x;
    int row0 = blockIdx.x * 32;
    int m = lane & 31;
    int half = lane >> 5;

    f32x16 acc[4];
#pragma unroll
    for (int t = 0; t < 4; ++t) acc[t] = (f32x16)(0.f);

    float bb[4];
#pragma unroll
    for (int t = 0; t < 4; ++t) bb[t] = bias[t * 32 + m];

    const ushort_t* arow = Abuf + (size_t)(row0 + m) * AK + half * 8;
    const ushort_t* wf = Wfrag + (size_t)lane * 8;

#pragma unroll
    for (int s = 0; s < 16; ++s) {
        bf16x8 afrag = *(const bf16x8*)(arow + s * 16);
#pragma unroll
        for (int t = 0; t < 4; ++t) {
            bf16x8 bfrag = *(const bf16x8*)(wf + (size_t)(t * 16 + s) * 64 * 8);
            acc[t] = __builtin_amdgcn_mfma_f32_32x32x16_bf16(afrag, bfrag, acc[t], 0, 0, 0);
        }
    }

#pragma unroll
    for (int t = 0; t < 4; ++t) {
#pragma unroll
        for (int r = 0; r < 16; ++r) {
            int rowL = (r & 3) + 8 * (r >> 2) + 4 * half;
            sm[rowL][t * 32 + m] = f2bf(fmaxf(acc[t][r] + bb[t], 0.f));
        }
    }
    __syncthreads();
    int seg = lane & 15;
    int rbase = lane >> 4;
#pragma unroll
    for (int it = 0; it < 8; ++it) {
        int rowL = rbase + it * 4;
        int4 chunk = *(const int4*)&sm[rowL][seg * 8];
        *(int4*)(y + (size_t)(row0 + rowL) * HDIM + seg * 8) = chunk;
    }
}

// ---------------- MFMA GEMM layer-3: relu -> per-graph pooled atomicAdd ----------

__global__ __launch_bounds__(64) void k_gemm_pool(const ushort_t* __restrict__ Abuf,
                                                  const ushort_t* __restrict__ Wfrag,
                                                  const float* __restrict__ bias,
                                                  float* __restrict__ pooled) {
    int lane = threadIdx.x;
    int row0 = blockIdx.x * 32;
    int m = lane & 31;
    int half = lane >> 5;

    f32x16 acc[4];
#pragma unroll
    for (int t = 0; t < 4; ++t) acc[t] = (f32x16)(0.f);

    float bb[4];
#pragma unroll
    for (int t = 0; t < 4; ++t) bb[t] = bias[t * 32 + m];

    const ushort_t* arow = Abuf + (size_t)(row0 + m) * AK + half * 8;
    const ushort_t* wf = Wfrag + (size_t)lane * 8;

#pragma unroll
    for (int s = 0; s < 16; ++s) {
        bf16x8 afrag = *(const bf16x8*)(arow + s * 16);
#pragma unroll
        for (int t = 0; t < 4; ++t) {
            bf16x8 bfrag = *(const bf16x8*)(wf + (size_t)(t * 16 + s) * 64 * 8);
            acc[t] = __builtin_amdgcn_mfma_f32_32x32x16_bf16(afrag, bfrag, acc[t], 0, 0, 0);
        }
    }

    int g0 = row0 / SEG;
    int bnd = (g0 + 1) * SEG;
    int straddle = (row0 + 31 >= bnd);

#pragma unroll
    for (int t = 0; t < 4; ++t) {
        float s0 = 0.f, s1 = 0.f;
#pragma unroll
        for (int r = 0; r < 16; ++r) {
            int row = row0 + (r & 3) + 8 * (r >> 2) + 4 * half;
            float v = fmaxf(acc[t][r] + bb[t], 0.f);
            if (row < bnd) s0 += v; else s1 += v;
        }
        s0 += __shfl_xor(s0, 32);
        s1 += __shfl_xor(s1, 32);
        if (half == 0) {
            atomicAdd(&pooled[g0 * HDIM + t * 32 + m], s0);
            if (straddle) atomicAdd(&pooled[(g0 + 1) * HDIM + t * 32 + m], s1);
        }
    }
}

// ---------------- mixup: bf16 y -> Abuf right half ----------------

__global__ void k_mixup_toA(const ushort_t* __restrict__ y, const int* __restrict__ perm,
                            const float* __restrict__ lam, ushort_t* __restrict__ Abuf) {
    int idx = blockIdx.x * 256 + threadIdx.x;
    int row = idx >> 5;
    int c4 = (idx & 31) * 4;
    float l = lam[0];
    float om = 1.f - l;
    int p = perm[row];
    ushort4 a = *(const ushort4*)(y + (size_t)row * HDIM + c4);
    ushort4 b = *(const ushort4*)(y + (size_t)p * HDIM + c4);
    ushort4 o;
    o.x = f2bf(l * bf2f(a.x) + om * bf2f(b.x));
    o.y = f2bf(l * bf2f(a.y) + om * bf2f(b.y));
    o.z = f2bf(l * bf2f(a.z) + om * bf2f(b.z));
    o.w = f2bf(l * bf2f(a.w) + om * bf2f(b.w));
    *(ushort4*)(Abuf + (size_t)row * AK + HDIM + c4) = o;
}

// ---------------- final: linear + log_softmax from pooled ----------------

__global__ __launch_bounds__(64) void k_final(const float* __restrict__ pooled,
                                              const float* __restrict__ Wlin,
                                              const float* __restrict__ blin,
                                              float* __restrict__ out) {
    int g = blockIdx.x;
    int lane = threadIdx.x;
    float2 v = *(const float2*)(pooled + (size_t)g * HDIM + lane * 2);
    float p[NOUT];
#pragma unroll
    for (int o = 0; o < NOUT; ++o)
        p[o] = v.x * Wlin[(size_t)(2 * lane) * NOUT + o] +
               v.y * Wlin[(size_t)(2 * lane + 1) * NOUT + o];
#pragma unroll
    for (int mask = 1; mask < 64; mask <<= 1)
#pragma unroll
        for (int o = 0; o < NOUT; ++o) p[o] += __shfl_xor(p[o], mask);
    if (lane == 0) {
        float lg[NOUT];
        float mx = -1e30f;
#pragma unroll
        for (int o = 0; o < NOUT; ++o) { lg[o] = p[o] + blin[o]; mx = fmaxf(mx, lg[o]); }
        float se = 0.f;
#pragma unroll
        for (int o = 0; o < NOUT; ++o) se += expf(lg[o] - mx);
        float lse = mx + logf(se);
#pragma unroll
        for (int o = 0; o < NOUT; ++o) out[g * NOUT + o] = lg[o] - lse;
    }
}

// ---------------- host ----------------

extern "C" void kernel_launch(void* const* d_in, const int* in_sizes, int n_in,
                              void* d_out, int out_size, void* d_ws, size_t ws_size,
                              hipStream_t stream) {
    const float* x0     = (const float*)d_in[0];
    const int*   edge   = (const int*)d_in[1];
    const int*   src    = edge;
    const int*   dst    = edge + N_EDGES;
    const float* lam    = (const float*)d_in[2];
    const int*   perm1  = (const int*)d_in[5];
    const int*   perm2  = (const int*)d_in[6];
    const float* W1_rel = (const float*)d_in[8];
    const float* b1_rel = (const float*)d_in[9];
    const float* W1_root= (const float*)d_in[10];
    const float* W2_rel = (const float*)d_in[11];
    const float* b2_rel = (const float*)d_in[12];
    const float* W2_root= (const float*)d_in[13];
    const float* W_lin  = (const float*)d_in[14];
    const float* b_lin  = (const float*)d_in[15];
    float* out = (float*)d_out;

    char* w = (char*)d_ws;
    size_t off = 0;
    auto alloc = [&](size_t bytes) -> void* {
        void* p = w + off;
        off = (off + bytes + 255) & ~(size_t)255;
        return p;
    };
    int* counts    = (int*)alloc((size_t)CSR_M * 4);
    int* cursor    = (int*)alloc((size_t)CSR_M * 4);
    int* partial   = (int*)alloc((size_t)CSR_M * 4);
    int* blocksums = (int*)alloc(512 * 4);
    int* blockoffs = (int*)alloc(512 * 4);
    int* row_ptr   = (int*)alloc((size_t)(CSR_M + 1) * 4);
    ushort_t* col  = (ushort_t*)alloc((size_t)N_EDGES * 2);
    ushort_t* Abuf   = (ushort_t*)alloc((size_t)N_NODES * AK * 2);
    ushort_t* ybuf   = (ushort_t*)alloc((size_t)N_NODES * HDIM * 2);
    ushort_t* Wfrag1 = (ushort_t*)alloc(32768 * 2);
    ushort_t* Wfrag2 = (ushort_t*)alloc(32768 * 2);
    float* pooled    = (float*)alloc((size_t)NGRAPH * HDIM * 4);

    hipMemsetAsync(counts, 0, (size_t)CSR_M * 4, stream);
    hipMemsetAsync(cursor, 0, (size_t)CSR_M * 4, stream);
    hipMemsetAsync(pooled, 0, (size_t)NGRAPH * HDIM * 4, stream);

    // CSR build (8-way sliced)
    k_count<<<N_EDGES / 256, 256, 0, stream>>>(dst, counts);
    k_scan_block<<<CSR_M / 1024, 256, 0, stream>>>(counts, partial, blocksums);
    k_scan_top<<<1, 512, 0, stream>>>(blocksums, blockoffs);
    k_rowptr<<<(CSR_M + 255) / 256, 256, 0, stream>>>(partial, blockoffs, row_ptr);
    k_fill<<<N_EDGES / 256, 256, 0, stream>>>(src, dst, row_ptr, cursor, col);

    // weight fragments
    k_wfrag<<<128, 256, 0, stream>>>(W1_rel, W1_root, Wfrag1);
    k_wfrag<<<128, 256, 0, stream>>>(W2_rel, W2_root, Wfrag2);

    const int aggGrid  = (N_NODES / 16) * 4;         // 12800
    const int gemmGrid = N_NODES / 32;
    const int elGrid   = (N_NODES * HDIM / 4) / 256;

    k_cast<<<elGrid, 256, 0, stream>>>(x0, Abuf);

    // layer 1
    k_aggregate<<<aggGrid, 256, 0, stream>>>(Abuf, row_ptr, col);
    k_gemm_mfma<<<gemmGrid, 64, 0, stream>>>(Abuf, Wfrag1, b1_rel, ybuf);
    k_mixup_toA<<<elGrid, 256, 0, stream>>>(ybuf, perm1, lam, Abuf);
    // layer 2
    k_aggregate<<<aggGrid, 256, 0, stream>>>(Abuf, row_ptr, col);
    k_gemm_mfma<<<gemmGrid, 64, 0, stream>>>(Abuf, Wfrag2, b2_rel, ybuf);
    k_mixup_toA<<<elGrid, 256, 0, stream>>>(ybuf, perm2, lam, Abuf);
    // layer 3 (mixup3 is a pooling no-op -> fused pool)
    k_aggregate<<<aggGrid, 256, 0, stream>>>(Abuf, row_ptr, col);
    k_gemm_pool<<<gemmGrid, 64, 0, stream>>>(Abuf, Wfrag2, b2_rel, pooled);

    // classifier + log_softmax
    k_final<<<NGRAPH, 64, 0, stream>>>(pooled, W_lin, b_lin, out);
}

// Round 6
// 396.359 us; speedup vs baseline: 1.6170x; 1.6170x over previous
//
#include <hip/hip_runtime.h>

#define N_NODES 51200
#define N_EDGES 819200
#define HDIM 128
#define AK 256          // GEMM K = 2*HDIM (agg | x)
#define NGRAPH 128
#define SEG 400
#define NOUT 10
#define NS 8            // CSR slices (one per XCD via blockIdx%8 heuristic)
#define CSR_M (NS * N_NODES)

typedef unsigned short ushort_t;
typedef __attribute__((ext_vector_type(8))) short bf16x8;
typedef __attribute__((ext_vector_type(16))) float f32x16;

static __device__ __forceinline__ unsigned short f2bf(float f) {
    unsigned int u = __float_as_uint(f);
    unsigned int r = (u + 0x7fffu + ((u >> 16) & 1u)) >> 16;  // RNE
    return (unsigned short)r;
}
static __device__ __forceinline__ float bf2f(unsigned short h) {
    return __uint_as_float(((unsigned int)h) << 16);
}

// ---------------- CSR build (slice-major fill for XCD write locality) ----------------

__global__ void k_count(const int* __restrict__ dst, int* __restrict__ counts) {
    int e = blockIdx.x * 256 + threadIdx.x;
    int s = blockIdx.x & 7;
    atomicAdd(&counts[s * N_NODES + dst[e]], 1);
}

// counts_sl[s*N+n] -> counts_nm[n*8+s] (node-major interleave for 2nd scan)
__global__ void k_tr(const int* __restrict__ csl, int* __restrict__ cnm) {
    int i = blockIdx.x * 256 + threadIdx.x;  // i over CSR_M
    int s = i >> 16;                          // i / N_NODES  (N_NODES = 51200 < 65536? no!)
    // N_NODES=51200 -> can't shift; compute properly:
    s = i / N_NODES;
    int n = i - s * N_NODES;
    cnm[n * 8 + s] = csl[i];
}

// block = 256 threads, 4 items/thread -> 1024 elements/block
__global__ void k_scan_block(const int* __restrict__ counts,
                             int* __restrict__ partial,
                             int* __restrict__ blocksums) {
    __shared__ int tsum[256];
    int tid = threadIdx.x;
    int base = blockIdx.x * 1024 + tid * 4;
    int4 c = *(const int4*)(counts + base);
    int s1 = c.x, s2 = s1 + c.y, s3 = s2 + c.z, s4 = s3 + c.w;
    tsum[tid] = s4;
    __syncthreads();
    for (int off = 1; off < 256; off <<= 1) {
        int t = (tid >= off) ? tsum[tid - off] : 0;
        __syncthreads();
        tsum[tid] += t;
        __syncthreads();
    }
    int excl = tsum[tid] - s4;
    int4 o;
    o.x = excl; o.y = excl + s1; o.z = excl + s2; o.w = excl + s3;
    *(int4*)(partial + base) = o;
    if (tid == 255) blocksums[blockIdx.x] = tsum[255];
}

// single block, 512 threads, scans up to 400 block sums
__global__ void k_scan_top(const int* __restrict__ blocksums, int* __restrict__ blockoffs,
                           int nvalid) {
    __shared__ int s[512];
    int tid = threadIdx.x;
    int v = (tid < nvalid) ? blocksums[tid] : 0;
    s[tid] = v;
    __syncthreads();
    for (int off = 1; off < 512; off <<= 1) {
        int t = (tid >= off) ? s[tid - off] : 0;
        __syncthreads();
        s[tid] += t;
        __syncthreads();
    }
    if (tid < nvalid) blockoffs[tid] = s[tid] - v;
}

__global__ void k_rowptr(const int* __restrict__ partial, const int* __restrict__ blockoffs,
                         int* __restrict__ row_ptr) {
    int i = blockIdx.x * 256 + threadIdx.x;
    if (i < CSR_M) row_ptr[i] = partial[i] + blockoffs[i >> 10];
    if (i == 0) row_ptr[CSR_M] = N_EDGES;
}

__global__ void k_fill(const int* __restrict__ src, const int* __restrict__ dst,
                       const int* __restrict__ rp_sl, int* __restrict__ cursor,
                       ushort_t* __restrict__ col_sl) {
    int e = blockIdx.x * 256 + threadIdx.x;
    int idx = (blockIdx.x & 7) * N_NODES + dst[e];
    int pos = rp_sl[idx] + atomicAdd(&cursor[idx], 1);
    col_sl[pos] = (ushort_t)src[e];
}

// regroup: slice-major col -> node-major col2 (node n's edges contiguous)
__global__ void k_regroup(const int* __restrict__ rp_sl, const int* __restrict__ rp_nm,
                          const ushort_t* __restrict__ col_sl, ushort_t* __restrict__ col2) {
    int n = blockIdx.x * 256 + threadIdx.x;
    if (n >= N_NODES) return;
    int base = rp_nm[n * 8];
#pragma unroll
    for (int s = 0; s < 8; ++s) {
        int b = rp_sl[s * N_NODES + n];
        int t = rp_sl[s * N_NODES + n + 1];
        for (int e = b; e < t; ++e) col2[base++] = col_sl[e];
    }
}

// ---------------- cast x0 -> Abuf right half (bf16) ----------------

__global__ void k_cast(const float* __restrict__ x, ushort_t* __restrict__ Abuf) {
    int idx = blockIdx.x * 256 + threadIdx.x;
    int row = idx >> 5;
    int c4 = (idx & 31) * 4;
    float4 v = *(const float4*)(x + (size_t)row * HDIM + c4);
    ushort4 h;
    h.x = f2bf(v.x); h.y = f2bf(v.y); h.z = f2bf(v.z); h.w = f2bf(v.w);
    *(ushort4*)(Abuf + (size_t)row * AK + HDIM + c4) = h;
}

// ---------------- aggregation: wave/node, row gather, unroll-8 ILP (proven R4) ------

__global__ __launch_bounds__(256) void k_aggregate(ushort_t* __restrict__ Abuf,
                                                   const int* __restrict__ rp_nm,
                                                   const ushort_t* __restrict__ col) {
    int wave = threadIdx.x >> 6;
    int lane = threadIdx.x & 63;
    int node = blockIdx.x * 4 + wave;
    int beg = rp_nm[node * 8];
    int end = rp_nm[node * 8 + 8];
    size_t fo = (size_t)lane * 2;

    float ax[8], ay[8];
#pragma unroll
    for (int j = 0; j < 8; ++j) { ax[j] = 0.f; ay[j] = 0.f; }

    const ushort_t* xsrc = Abuf + HDIM;
    int e = beg;
    for (; e + 8 <= end; e += 8) {
        int c[8];
#pragma unroll
        for (int j = 0; j < 8; ++j) c[j] = (int)col[e + j];
#pragma unroll
        for (int j = 0; j < 8; ++j) {
            unsigned int v = *(const unsigned int*)(xsrc + (size_t)c[j] * AK + fo);
            ax[j] += __uint_as_float(v << 16);
            ay[j] += __uint_as_float(v & 0xffff0000u);
        }
    }
    for (; e < end; ++e) {
        unsigned int v = *(const unsigned int*)(xsrc + (size_t)col[e] * AK + fo);
        ax[0] += __uint_as_float(v << 16);
        ay[0] += __uint_as_float(v & 0xffff0000u);
    }

    float sx = (ax[0] + ax[1]) + (ax[2] + ax[3]) + ((ax[4] + ax[5]) + (ax[6] + ax[7]));
    float sy = (ay[0] + ay[1]) + (ay[2] + ay[3]) + ((ay[4] + ay[5]) + (ay[6] + ay[7]));
    unsigned int packed = (unsigned int)f2bf(sx) | ((unsigned int)f2bf(sy) << 16);
    *(unsigned int*)(Abuf + (size_t)node * AK + fo) = packed;
}

// ---------------- weight fragment prep ----------------

__global__ void k_wfrag(const float* __restrict__ Wrel, const float* __restrict__ Wroot,
                        ushort_t* __restrict__ dstF) {
    int tid = blockIdx.x * 256 + threadIdx.x;  // 0..32767
    int j = tid & 7;
    int l = (tid >> 3) & 63;
    int s = (tid >> 9) & 15;
    int t = tid >> 13;
    int k = 16 * s + (l >> 5) * 8 + j;
    int n = 32 * t + (l & 31);
    float v = (k < HDIM) ? Wrel[(size_t)k * HDIM + n] : Wroot[(size_t)(k - HDIM) * HDIM + n];
    dstF[tid] = f2bf(v);
}

// ---------------- MFMA GEMM (layers 1-2): y = relu([agg|x] @ W + b) -------------

__global__ __launch_bounds__(64) void k_gemm_mfma(const ushort_t* __restrict__ Abuf,
                                                  const ushort_t* __restrict__ Wfrag,
                                                  const float* __restrict__ bias,
                                                  ushort_t* __restrict__ y) {
    __shared__ ushort_t sm[32][136];
    int lane = threadIdx.x;
    int row0 = blockIdx.x * 32;
    int m = lane & 31;
    int half = lane >> 5;

    f32x16 acc[4];
#pragma unroll
    for (int t = 0; t < 4; ++t) acc[t] = (f32x16)(0.f);

    float bb[4];
#pragma unroll
    for (int t = 0; t < 4; ++t) bb[t] = bias[t * 32 + m];

    const ushort_t* arow = Abuf + (size_t)(row0 + m) * AK + half * 8;
    const ushort_t* wf = Wfrag + (size_t)lane * 8;

#pragma unroll
    for (int s = 0; s < 16; ++s) {
        bf16x8 afrag = *(const bf16x8*)(arow + s * 16);
#pragma unroll
        for (int t = 0; t < 4; ++t) {
            bf16x8 bfrag = *(const bf16x8*)(wf + (size_t)(t * 16 + s) * 64 * 8);
            acc[t] = __builtin_amdgcn_mfma_f32_32x32x16_bf16(afrag, bfrag, acc[t], 0, 0, 0);
        }
    }

#pragma unroll
    for (int t = 0; t < 4; ++t) {
#pragma unroll
        for (int r = 0; r < 16; ++r) {
            int rowL = (r & 3) + 8 * (r >> 2) + 4 * half;
            sm[rowL][t * 32 + m] = f2bf(fmaxf(acc[t][r] + bb[t], 0.f));
        }
    }
    __syncthreads();
    int seg = lane & 15;
    int rbase = lane >> 4;
#pragma unroll
    for (int it = 0; it < 8; ++it) {
        int rowL = rbase + it * 4;
        int4 chunk = *(const int4*)&sm[rowL][seg * 8];
        *(int4*)(y + (size_t)(row0 + rowL) * HDIM + seg * 8) = chunk;
    }
}

// ---------------- MFMA GEMM layer-3: relu -> per-graph pooled atomicAdd ----------

__global__ __launch_bounds__(64) void k_gemm_pool(const ushort_t* __restrict__ Abuf,
                                                  const ushort_t* __restrict__ Wfrag,
                                                  const float* __restrict__ bias,
                                                  float* __restrict__ pooled) {
    int lane = threadIdx.x;
    int row0 = blockIdx.x * 32;
    int m = lane & 31;
    int half = lane >> 5;

    f32x16 acc[4];
#pragma unroll
    for (int t = 0; t < 4; ++t) acc[t] = (f32x16)(0.f);

    float bb[4];
#pragma unroll
    for (int t = 0; t < 4; ++t) bb[t] = bias[t * 32 + m];

    const ushort_t* arow = Abuf + (size_t)(row0 + m) * AK + half * 8;
    const ushort_t* wf = Wfrag + (size_t)lane * 8;

#pragma unroll
    for (int s = 0; s < 16; ++s) {
        bf16x8 afrag = *(const bf16x8*)(arow + s * 16);
#pragma unroll
        for (int t = 0; t < 4; ++t) {
            bf16x8 bfrag = *(const bf16x8*)(wf + (size_t)(t * 16 + s) * 64 * 8);
            acc[t] = __builtin_amdgcn_mfma_f32_32x32x16_bf16(afrag, bfrag, acc[t], 0, 0, 0);
        }
    }

    int g0 = row0 / SEG;
    int bnd = (g0 + 1) * SEG;
    int straddle = (row0 + 31 >= bnd);

#pragma unroll
    for (int t = 0; t < 4; ++t) {
        float s0 = 0.f, s1 = 0.f;
#pragma unroll
        for (int r = 0; r < 16; ++r) {
            int row = row0 + (r & 3) + 8 * (r >> 2) + 4 * half;
            float v = fmaxf(acc[t][r] + bb[t], 0.f);
            if (row < bnd) s0 += v; else s1 += v;
        }
        s0 += __shfl_xor(s0, 32);
        s1 += __shfl_xor(s1, 32);
        if (half == 0) {
            atomicAdd(&pooled[g0 * HDIM + t * 32 + m], s0);
            if (straddle) atomicAdd(&pooled[(g0 + 1) * HDIM + t * 32 + m], s1);
        }
    }
}

// ---------------- mixup: bf16 y -> Abuf right half ----------------

__global__ void k_mixup_toA(const ushort_t* __restrict__ y, const int* __restrict__ perm,
                            const float* __restrict__ lam, ushort_t* __restrict__ Abuf) {
    int idx = blockIdx.x * 256 + threadIdx.x;
    int row = idx >> 5;
    int c4 = (idx & 31) * 4;
    float l = lam[0];
    float om = 1.f - l;
    int p = perm[row];
    ushort4 a = *(const ushort4*)(y + (size_t)row * HDIM + c4);
    ushort4 b = *(const ushort4*)(y + (size_t)p * HDIM + c4);
    ushort4 o;
    o.x = f2bf(l * bf2f(a.x) + om * bf2f(b.x));
    o.y = f2bf(l * bf2f(a.y) + om * bf2f(b.y));
    o.z = f2bf(l * bf2f(a.z) + om * bf2f(b.z));
    o.w = f2bf(l * bf2f(a.w) + om * bf2f(b.w));
    *(ushort4*)(Abuf + (size_t)row * AK + HDIM + c4) = o;
}

// ---------------- final: linear + log_softmax from pooled ----------------

__global__ __launch_bounds__(64) void k_final(const float* __restrict__ pooled,
                                              const float* __restrict__ Wlin,
                                              const float* __restrict__ blin,
                                              float* __restrict__ out) {
    int g = blockIdx.x;
    int lane = threadIdx.x;
    float2 v = *(const float2*)(pooled + (size_t)g * HDIM + lane * 2);
    float p[NOUT];
#pragma unroll
    for (int o = 0; o < NOUT; ++o)
        p[o] = v.x * Wlin[(size_t)(2 * lane) * NOUT + o] +
               v.y * Wlin[(size_t)(2 * lane + 1) * NOUT + o];
#pragma unroll
    for (int mask = 1; mask < 64; mask <<= 1)
#pragma unroll
        for (int o = 0; o < NOUT; ++o) p[o] += __shfl_xor(p[o], mask);
    if (lane == 0) {
        float lg[NOUT];
        float mx = -1e30f;
#pragma unroll
        for (int o = 0; o < NOUT; ++o) { lg[o] = p[o] + blin[o]; mx = fmaxf(mx, lg[o]); }
        float se = 0.f;
#pragma unroll
        for (int o = 0; o < NOUT; ++o) se += expf(lg[o] - mx);
        float lse = mx + logf(se);
#pragma unroll
        for (int o = 0; o < NOUT; ++o) out[g * NOUT + o] = lg[o] - lse;
    }
}

// ---------------- host ----------------

extern "C" void kernel_launch(void* const* d_in, const int* in_sizes, int n_in,
                              void* d_out, int out_size, void* d_ws, size_t ws_size,
                              hipStream_t stream) {
    const float* x0     = (const float*)d_in[0];
    const int*   edge   = (const int*)d_in[1];
    const int*   src    = edge;
    const int*   dst    = edge + N_EDGES;
    const float* lam    = (const float*)d_in[2];
    const int*   perm1  = (const int*)d_in[5];
    const int*   perm2  = (const int*)d_in[6];
    const float* W1_rel = (const float*)d_in[8];
    const float* b1_rel = (const float*)d_in[9];
    const float* W1_root= (const float*)d_in[10];
    const float* W2_rel = (const float*)d_in[11];
    const float* b2_rel = (const float*)d_in[12];
    const float* W2_root= (const float*)d_in[13];
    const float* W_lin  = (const float*)d_in[14];
    const float* b_lin  = (const float*)d_in[15];
    float* out = (float*)d_out;

    char* w = (char*)d_ws;
    size_t off = 0;
    auto alloc = [&](size_t bytes) -> void* {
        void* p = w + off;
        off = (off + bytes + 255) & ~(size_t)255;
        return p;
    };
    int* counts_sl = (int*)alloc((size_t)CSR_M * 4);
    int* counts_nm = (int*)alloc((size_t)CSR_M * 4);
    int* cursor    = (int*)alloc((size_t)CSR_M * 4);
    int* partialA  = (int*)alloc((size_t)CSR_M * 4);
    int* partialB  = (int*)alloc((size_t)CSR_M * 4);
    int* blocksumsA = (int*)alloc(512 * 4);
    int* blockoffsA = (int*)alloc(512 * 4);
    int* blocksumsB = (int*)alloc(512 * 4);
    int* blockoffsB = (int*)alloc(512 * 4);
    int* rp_sl     = (int*)alloc((size_t)(CSR_M + 1) * 4);
    int* rp_nm     = (int*)alloc((size_t)(CSR_M + 1) * 4);
    ushort_t* col_sl = (ushort_t*)alloc((size_t)N_EDGES * 2);
    ushort_t* col2   = (ushort_t*)alloc((size_t)N_EDGES * 2);
    ushort_t* Abuf   = (ushort_t*)alloc((size_t)N_NODES * AK * 2);
    ushort_t* ybuf   = (ushort_t*)alloc((size_t)N_NODES * HDIM * 2);
    ushort_t* Wfrag1 = (ushort_t*)alloc(32768 * 2);
    ushort_t* Wfrag2 = (ushort_t*)alloc(32768 * 2);
    float* pooled    = (float*)alloc((size_t)NGRAPH * HDIM * 4);

    hipMemsetAsync(counts_sl, 0, (size_t)CSR_M * 4, stream);
    hipMemsetAsync(cursor, 0, (size_t)CSR_M * 4, stream);
    hipMemsetAsync(pooled, 0, (size_t)NGRAPH * HDIM * 4, stream);

    // CSR build: slice-major fill + node-major row_ptr + regroup
    k_count<<<N_EDGES / 256, 256, 0, stream>>>(dst, counts_sl);
    k_tr<<<CSR_M / 256, 256, 0, stream>>>(counts_sl, counts_nm);
    k_scan_block<<<CSR_M / 1024, 256, 0, stream>>>(counts_sl, partialA, blocksumsA);
    k_scan_top<<<1, 512, 0, stream>>>(blocksumsA, blockoffsA, CSR_M / 1024);
    k_rowptr<<<(CSR_M + 255) / 256, 256, 0, stream>>>(partialA, blockoffsA, rp_sl);
    k_scan_block<<<CSR_M / 1024, 256, 0, stream>>>(counts_nm, partialB, blocksumsB);
    k_scan_top<<<1, 512, 0, stream>>>(blocksumsB, blockoffsB, CSR_M / 1024);
    k_rowptr<<<(CSR_M + 255) / 256, 256, 0, stream>>>(partialB, blockoffsB, rp_nm);
    k_fill<<<N_EDGES / 256, 256, 0, stream>>>(src, dst, rp_sl, cursor, col_sl);
    k_regroup<<<(N_NODES + 255) / 256, 256, 0, stream>>>(rp_sl, rp_nm, col_sl, col2);

    // weight fragments
    k_wfrag<<<128, 256, 0, stream>>>(W1_rel, W1_root, Wfrag1);
    k_wfrag<<<128, 256, 0, stream>>>(W2_rel, W2_root, Wfrag2);

    const int aggGrid  = N_NODES / 4;
    const int gemmGrid = N_NODES / 32;
    const int elGrid   = (N_NODES * HDIM / 4) / 256;

    k_cast<<<elGrid, 256, 0, stream>>>(x0, Abuf);

    // layer 1
    k_aggregate<<<aggGrid, 256, 0, stream>>>(Abuf, rp_nm, col2);
    k_gemm_mfma<<<gemmGrid, 64, 0, stream>>>(Abuf, Wfrag1, b1_rel, ybuf);
    k_mixup_toA<<<elGrid, 256, 0, stream>>>(ybuf, perm1, lam, Abuf);
    // layer 2
    k_aggregate<<<aggGrid, 256, 0, stream>>>(Abuf, rp_nm, col2);
    k_gemm_mfma<<<gemmGrid, 64, 0, stream>>>(Abuf, Wfrag2, b2_rel, ybuf);
    k_mixup_toA<<<elGrid, 256, 0, stream>>>(ybuf, perm2, lam, Abuf);
    // layer 3 (mixup3 is a pooling no-op -> fused pool)
    k_aggregate<<<aggGrid, 256, 0, stream>>>(Abuf, rp_nm, col2);
    k_gemm_pool<<<gemmGrid, 64, 0, stream>>>(Abuf, Wfrag2, b2_rel, pooled);

    // classifier + log_softmax
    k_final<<<NGRAPH, 64, 0, stream>>>(pooled, W_lin, b_lin, out);
}

// Round 7
// 388.070 us; speedup vs baseline: 1.6516x; 1.0214x over previous
//
#include <hip/hip_runtime.h>

#define N_NODES 51200
#define N_EDGES 819200
#define HDIM 128
#define AK 256          // GEMM K = 2*HDIM (agg | x)
#define NGRAPH 128
#define SEG 400
#define NOUT 10
#define NS 8            // CSR slices (one per XCD via blockIdx%8 heuristic)
#define CSR_M (NS * N_NODES)

typedef unsigned short ushort_t;
typedef __attribute__((ext_vector_type(8))) short bf16x8;
typedef __attribute__((ext_vector_type(16))) float f32x16;

static __device__ __forceinline__ unsigned short f2bf(float f) {
    unsigned int u = __float_as_uint(f);
    unsigned int r = (u + 0x7fffu + ((u >> 16) & 1u)) >> 16;  // RNE
    return (unsigned short)r;
}
static __device__ __forceinline__ float bf2f(unsigned short h) {
    return __uint_as_float(((unsigned int)h) << 16);
}

// ---------------- CSR build (slice-major fill for XCD write locality) ----------------

__global__ void k_count(const int* __restrict__ dst, int* __restrict__ counts) {
    int e = blockIdx.x * 256 + threadIdx.x;
    int s = blockIdx.x & 7;
    atomicAdd(&counts[s * N_NODES + dst[e]], 1);
}

// block = 256 threads, 4 items/thread -> 1024 elements/block; grid = CSR_M/1024 = 400
__global__ void k_scan_block(const int* __restrict__ counts,
                             int* __restrict__ partial,
                             int* __restrict__ blocksums) {
    __shared__ int tsum[256];
    int tid = threadIdx.x;
    int base = blockIdx.x * 1024 + tid * 4;
    int4 c = *(const int4*)(counts + base);
    int s1 = c.x, s2 = s1 + c.y, s3 = s2 + c.z, s4 = s3 + c.w;
    tsum[tid] = s4;
    __syncthreads();
    for (int off = 1; off < 256; off <<= 1) {
        int t = (tid >= off) ? tsum[tid - off] : 0;
        __syncthreads();
        tsum[tid] += t;
        __syncthreads();
    }
    int excl = tsum[tid] - s4;
    int4 o;
    o.x = excl; o.y = excl + s1; o.z = excl + s2; o.w = excl + s3;
    *(int4*)(partial + base) = o;
    if (tid == 255) blocksums[blockIdx.x] = tsum[255];
}

// single block, 512 threads, scans 400 block sums
__global__ void k_scan_top(const int* __restrict__ blocksums, int* __restrict__ blockoffs) {
    __shared__ int s[512];
    int tid = threadIdx.x;
    int v = (tid < 400) ? blocksums[tid] : 0;
    s[tid] = v;
    __syncthreads();
    for (int off = 1; off < 512; off <<= 1) {
        int t = (tid >= off) ? s[tid - off] : 0;
        __syncthreads();
        s[tid] += t;
        __syncthreads();
    }
    if (tid < 400) blockoffs[tid] = s[tid] - v;
}

// fill: rp_sl computed inline from partial+blockoffs
__global__ void k_fill(const int* __restrict__ src, const int* __restrict__ dst,
                       const int* __restrict__ partial, const int* __restrict__ blockoffs,
                       int* __restrict__ cursor, ushort_t* __restrict__ col_sl) {
    int e = blockIdx.x * 256 + threadIdx.x;
    int idx = (blockIdx.x & 7) * N_NODES + dst[e];
    int rp = partial[idx] + blockoffs[idx >> 10];
    int pos = rp + atomicAdd(&cursor[idx], 1);
    col_sl[pos] = (ushort_t)src[e];
}

// regroup: slice-major col -> node-contiguous col2; bases via wave-scanned atomic bump
__global__ __launch_bounds__(256) void k_regroup(const int* __restrict__ counts,
                                                 const int* __restrict__ partial,
                                                 const int* __restrict__ blockoffs,
                                                 const ushort_t* __restrict__ col_sl,
                                                 ushort_t* __restrict__ col2,
                                                 int2* __restrict__ nodeseg,
                                                 int* __restrict__ gtotal) {
    int n = blockIdx.x * 256 + threadIdx.x;
    int lane = threadIdx.x & 63;

    int deg = 0;
#pragma unroll
    for (int s = 0; s < 8; ++s) deg += counts[s * N_NODES + n];

    // wave inclusive scan of deg
    int incl = deg;
#pragma unroll
    for (int off = 1; off < 64; off <<= 1) {
        int t = __shfl_up(incl, off);
        if (lane >= off) incl += t;
    }
    int excl = incl - deg;
    int wtotal = __shfl(incl, 63);
    int wbase = 0;
    if (lane == 0) wbase = atomicAdd(gtotal, wtotal);
    wbase = __shfl(wbase, 0);
    int base = wbase + excl;

    nodeseg[n] = make_int2(base, base + deg);

#pragma unroll
    for (int s = 0; s < 8; ++s) {
        int i = s * N_NODES + n;
        int b = partial[i] + blockoffs[i >> 10];
        int cnt = counts[i];
        for (int e = 0; e < cnt; ++e) col2[base++] = col_sl[b + e];
    }
}

// ---------------- prep: cast x0 -> Abuf right half, build both Wfrags, zero pooled ----
// grid = 6400 (cast) + 128 (wfrag1) + 128 (wfrag2) + 64 (pooled zero) = 6720 blocks

__global__ void k_prep(const float* __restrict__ x, ushort_t* __restrict__ Abuf,
                       const float* __restrict__ W1rel, const float* __restrict__ W1root,
                       const float* __restrict__ W2rel, const float* __restrict__ W2root,
                       ushort_t* __restrict__ Wfrag1, ushort_t* __restrict__ Wfrag2,
                       float* __restrict__ pooled) {
    int b = blockIdx.x;
    if (b < 6400) {
        int idx = b * 256 + threadIdx.x;
        int row = idx >> 5;
        int c4 = (idx & 31) * 4;
        float4 v = *(const float4*)(x + (size_t)row * HDIM + c4);
        ushort4 h;
        h.x = f2bf(v.x); h.y = f2bf(v.y); h.z = f2bf(v.z); h.w = f2bf(v.w);
        *(ushort4*)(Abuf + (size_t)row * AK + HDIM + c4) = h;
    } else if (b < 6656) {
        int w2 = (b >= 6528);
        int tid = (b - (w2 ? 6528 : 6400)) * 256 + threadIdx.x;  // 0..32767
        const float* Wrel  = w2 ? W2rel : W1rel;
        const float* Wroot = w2 ? W2root : W1root;
        ushort_t* dstF     = w2 ? Wfrag2 : Wfrag1;
        int j = tid & 7;
        int l = (tid >> 3) & 63;
        int s = (tid >> 9) & 15;
        int t = tid >> 13;
        int k = 16 * s + (l >> 5) * 8 + j;
        int n = 32 * t + (l & 31);
        float v = (k < HDIM) ? Wrel[(size_t)k * HDIM + n]
                             : Wroot[(size_t)(k - HDIM) * HDIM + n];
        dstF[tid] = f2bf(v);
    } else {
        int i = (b - 6656) * 256 + threadIdx.x;  // 0..16383
        pooled[i] = 0.f;
    }
}

// ---------------- aggregation: wave/node, row gather, unroll-8 ILP (proven R4) ------

__global__ __launch_bounds__(256) void k_aggregate(ushort_t* __restrict__ Abuf,
                                                   const int2* __restrict__ nodeseg,
                                                   const ushort_t* __restrict__ col) {
    int wave = threadIdx.x >> 6;
    int lane = threadIdx.x & 63;
    int node = blockIdx.x * 4 + wave;
    int2 se = nodeseg[node];
    int beg = se.x;
    int end = se.y;
    size_t fo = (size_t)lane * 2;

    float ax[8], ay[8];
#pragma unroll
    for (int j = 0; j < 8; ++j) { ax[j] = 0.f; ay[j] = 0.f; }

    const ushort_t* xsrc = Abuf + HDIM;
    int e = beg;
    for (; e + 8 <= end; e += 8) {
        int c[8];
#pragma unroll
        for (int j = 0; j < 8; ++j) c[j] = (int)col[e + j];
#pragma unroll
        for (int j = 0; j < 8; ++j) {
            unsigned int v = *(const unsigned int*)(xsrc + (size_t)c[j] * AK + fo);
            ax[j] += __uint_as_float(v << 16);
            ay[j] += __uint_as_float(v & 0xffff0000u);
        }
    }
    for (; e < end; ++e) {
        unsigned int v = *(const unsigned int*)(xsrc + (size_t)col[e] * AK + fo);
        ax[0] += __uint_as_float(v << 16);
        ay[0] += __uint_as_float(v & 0xffff0000u);
    }

    float sx = (ax[0] + ax[1]) + (ax[2] + ax[3]) + ((ax[4] + ax[5]) + (ax[6] + ax[7]));
    float sy = (ay[0] + ay[1]) + (ay[2] + ay[3]) + ((ay[4] + ay[5]) + (ay[6] + ay[7]));
    unsigned int packed = (unsigned int)f2bf(sx) | ((unsigned int)f2bf(sy) << 16);
    *(unsigned int*)(Abuf + (size_t)node * AK + fo) = packed;
}

// ---------------- MFMA GEMM (layers 1-2): y = relu([agg|x] @ W + b) -------------

__global__ __launch_bounds__(64) void k_gemm_mfma(const ushort_t* __restrict__ Abuf,
                                                  const ushort_t* __restrict__ Wfrag,
                                                  const float* __restrict__ bias,
                                                  ushort_t* __restrict__ y) {
    __shared__ ushort_t sm[32][136];
    int lane = threadIdx.x;
    int row0 = blockIdx.x * 32;
    int m = lane & 31;
    int half = lane >> 5;

    f32x16 acc[4];
#pragma unroll
    for (int t = 0; t < 4; ++t) acc[t] = (f32x16)(0.f);

    float bb[4];
#pragma unroll
    for (int t = 0; t < 4; ++t) bb[t] = bias[t * 32 + m];

    const ushort_t* arow = Abuf + (size_t)(row0 + m) * AK + half * 8;
    const ushort_t* wf = Wfrag + (size_t)lane * 8;

#pragma unroll
    for (int s = 0; s < 16; ++s) {
        bf16x8 afrag = *(const bf16x8*)(arow + s * 16);
#pragma unroll
        for (int t = 0; t < 4; ++t) {
            bf16x8 bfrag = *(const bf16x8*)(wf + (size_t)(t * 16 + s) * 64 * 8);
            acc[t] = __builtin_amdgcn_mfma_f32_32x32x16_bf16(afrag, bfrag, acc[t], 0, 0, 0);
        }
    }

#pragma unroll
    for (int t = 0; t < 4; ++t) {
#pragma unroll
        for (int r = 0; r < 16; ++r) {
            int rowL = (r & 3) + 8 * (r >> 2) + 4 * half;
            sm[rowL][t * 32 + m] = f2bf(fmaxf(acc[t][r] + bb[t], 0.f));
        }
    }
    __syncthreads();
    int seg = lane & 15;
    int rbase = lane >> 4;
#pragma unroll
    for (int it = 0; it < 8; ++it) {
        int rowL = rbase + it * 4;
        int4 chunk = *(const int4*)&sm[rowL][seg * 8];
        *(int4*)(y + (size_t)(row0 + rowL) * HDIM + seg * 8) = chunk;
    }
}

// ---------------- MFMA GEMM layer-3: relu -> per-graph pooled atomicAdd ----------

__global__ __launch_bounds__(64) void k_gemm_pool(const ushort_t* __restrict__ Abuf,
                                                  const ushort_t* __restrict__ Wfrag,
                                                  const float* __restrict__ bias,
                                                  float* __restrict__ pooled) {
    int lane = threadIdx.x;
    int row0 = blockIdx.x * 32;
    int m = lane & 31;
    int half = lane >> 5;

    f32x16 acc[4];
#pragma unroll
    for (int t = 0; t < 4; ++t) acc[t] = (f32x16)(0.f);

    float bb[4];
#pragma unroll
    for (int t = 0; t < 4; ++t) bb[t] = bias[t * 32 + m];

    const ushort_t* arow = Abuf + (size_t)(row0 + m) * AK + half * 8;
    const ushort_t* wf = Wfrag + (size_t)lane * 8;

#pragma unroll
    for (int s = 0; s < 16; ++s) {
        bf16x8 afrag = *(const bf16x8*)(arow + s * 16);
#pragma unroll
        for (int t = 0; t < 4; ++t) {
            bf16x8 bfrag = *(const bf16x8*)(wf + (size_t)(t * 16 + s) * 64 * 8);
            acc[t] = __builtin_amdgcn_mfma_f32_32x32x16_bf16(afrag, bfrag, acc[t], 0, 0, 0);
        }
    }

    int g0 = row0 / SEG;
    int bnd = (g0 + 1) * SEG;
    int straddle = (row0 + 31 >= bnd);

#pragma unroll
    for (int t = 0; t < 4; ++t) {
        float s0 = 0.f, s1 = 0.f;
#pragma unroll
        for (int r = 0; r < 16; ++r) {
            int row = row0 + (r & 3) + 8 * (r >> 2) + 4 * half;
            float v = fmaxf(acc[t][r] + bb[t], 0.f);
            if (row < bnd) s0 += v; else s1 += v;
        }
        s0 += __shfl_xor(s0, 32);
        s1 += __shfl_xor(s1, 32);
        if (half == 0) {
            atomicAdd(&pooled[g0 * HDIM + t * 32 + m], s0);
            if (straddle) atomicAdd(&pooled[(g0 + 1) * HDIM + t * 32 + m], s1);
        }
    }
}

// ---------------- mixup: bf16 y -> Abuf right half ----------------

__global__ void k_mixup_toA(const ushort_t* __restrict__ y, const int* __restrict__ perm,
                            const float* __restrict__ lam, ushort_t* __restrict__ Abuf) {
    int idx = blockIdx.x * 256 + threadIdx.x;
    int row = idx >> 5;
    int c4 = (idx & 31) * 4;
    float l = lam[0];
    float om = 1.f - l;
    int p = perm[row];
    ushort4 a = *(const ushort4*)(y + (size_t)row * HDIM + c4);
    ushort4 b = *(const ushort4*)(y + (size_t)p * HDIM + c4);
    ushort4 o;
    o.x = f2bf(l * bf2f(a.x) + om * bf2f(b.x));
    o.y = f2bf(l * bf2f(a.y) + om * bf2f(b.y));
    o.z = f2bf(l * bf2f(a.z) + om * bf2f(b.z));
    o.w = f2bf(l * bf2f(a.w) + om * bf2f(b.w));
    *(ushort4*)(Abuf + (size_t)row * AK + HDIM + c4) = o;
}

// ---------------- final: linear + log_softmax from pooled ----------------

__global__ __launch_bounds__(64) void k_final(const float* __restrict__ pooled,
                                              const float* __restrict__ Wlin,
                                              const float* __restrict__ blin,
                                              float* __restrict__ out) {
    int g = blockIdx.x;
    int lane = threadIdx.x;
    float2 v = *(const float2*)(pooled + (size_t)g * HDIM + lane * 2);
    float p[NOUT];
#pragma unroll
    for (int o = 0; o < NOUT; ++o)
        p[o] = v.x * Wlin[(size_t)(2 * lane) * NOUT + o] +
               v.y * Wlin[(size_t)(2 * lane + 1) * NOUT + o];
#pragma unroll
    for (int mask = 1; mask < 64; mask <<= 1)
#pragma unroll
        for (int o = 0; o < NOUT; ++o) p[o] += __shfl_xor(p[o], mask);
    if (lane == 0) {
        float lg[NOUT];
        float mx = -1e30f;
#pragma unroll
        for (int o = 0; o < NOUT; ++o) { lg[o] = p[o] + blin[o]; mx = fmaxf(mx, lg[o]); }
        float se = 0.f;
#pragma unroll
        for (int o = 0; o < NOUT; ++o) se += expf(lg[o] - mx);
        float lse = mx + logf(se);
#pragma unroll
        for (int o = 0; o < NOUT; ++o) out[g * NOUT + o] = lg[o] - lse;
    }
}

// ---------------- host ----------------

extern "C" void kernel_launch(void* const* d_in, const int* in_sizes, int n_in,
                              void* d_out, int out_size, void* d_ws, size_t ws_size,
                              hipStream_t stream) {
    const float* x0     = (const float*)d_in[0];
    const int*   edge   = (const int*)d_in[1];
    const int*   src    = edge;
    const int*   dst    = edge + N_EDGES;
    const float* lam    = (const float*)d_in[2];
    const int*   perm1  = (const int*)d_in[5];
    const int*   perm2  = (const int*)d_in[6];
    const float* W1_rel = (const float*)d_in[8];
    const float* b1_rel = (const float*)d_in[9];
    const float* W1_root= (const float*)d_in[10];
    const float* W2_rel = (const float*)d_in[11];
    const float* b2_rel = (const float*)d_in[12];
    const float* W2_root= (const float*)d_in[13];
    const float* W_lin  = (const float*)d_in[14];
    const float* b_lin  = (const float*)d_in[15];
    float* out = (float*)d_out;

    char* w = (char*)d_ws;
    size_t off = 0;
    auto alloc = [&](size_t bytes) -> void* {
        void* p = w + off;
        off = (off + bytes + 255) & ~(size_t)255;
        return p;
    };
    // counts, cursor, gtotal contiguous -> ONE memset
    int* counts    = (int*)alloc((size_t)CSR_M * 4);
    int* cursor    = (int*)alloc((size_t)CSR_M * 4);
    int* gtotal    = (int*)alloc(256);
    size_t zero_bytes = (size_t)((char*)gtotal - (char*)counts) + 256;
    int* partial   = (int*)alloc((size_t)CSR_M * 4);
    int* blocksums = (int*)alloc(512 * 4);
    int* blockoffs = (int*)alloc(512 * 4);
    ushort_t* col_sl = (ushort_t*)alloc((size_t)N_EDGES * 2);
    ushort_t* col2   = (ushort_t*)alloc((size_t)N_EDGES * 2);
    int2* nodeseg    = (int2*)alloc((size_t)N_NODES * 8);
    ushort_t* Abuf   = (ushort_t*)alloc((size_t)N_NODES * AK * 2);
    ushort_t* ybuf   = (ushort_t*)alloc((size_t)N_NODES * HDIM * 2);
    ushort_t* Wfrag1 = (ushort_t*)alloc(32768 * 2);
    ushort_t* Wfrag2 = (ushort_t*)alloc(32768 * 2);
    float* pooled    = (float*)alloc((size_t)NGRAPH * HDIM * 4);

    hipMemsetAsync(counts, 0, zero_bytes, stream);

    // CSR build: count -> scan -> fill(slice-major) -> regroup(node-contiguous)
    k_count<<<N_EDGES / 256, 256, 0, stream>>>(dst, counts);
    k_scan_block<<<CSR_M / 1024, 256, 0, stream>>>(counts, partial, blocksums);
    k_scan_top<<<1, 512, 0, stream>>>(blocksums, blockoffs);
    k_fill<<<N_EDGES / 256, 256, 0, stream>>>(src, dst, partial, blockoffs, cursor, col_sl);
    k_regroup<<<N_NODES / 256, 256, 0, stream>>>(counts, partial, blockoffs,
                                                 col_sl, col2, nodeseg, gtotal);

    // prep: cast + wfrag1 + wfrag2 + zero pooled (one kernel)
    k_prep<<<6720, 256, 0, stream>>>(x0, Abuf, W1_rel, W1_root, W2_rel, W2_root,
                                     Wfrag1, Wfrag2, pooled);

    const int aggGrid  = N_NODES / 4;
    const int gemmGrid = N_NODES / 32;
    const int elGrid   = (N_NODES * HDIM / 4) / 256;

    // layer 1
    k_aggregate<<<aggGrid, 256, 0, stream>>>(Abuf, nodeseg, col2);
    k_gemm_mfma<<<gemmGrid, 64, 0, stream>>>(Abuf, Wfrag1, b1_rel, ybuf);
    k_mixup_toA<<<elGrid, 256, 0, stream>>>(ybuf, perm1, lam, Abuf);
    // layer 2
    k_aggregate<<<aggGrid, 256, 0, stream>>>(Abuf, nodeseg, col2);
    k_gemm_mfma<<<gemmGrid, 64, 0, stream>>>(Abuf, Wfrag2, b2_rel, ybuf);
    k_mixup_toA<<<elGrid, 256, 0, stream>>>(ybuf, perm2, lam, Abuf);
    // layer 3 (mixup3 is a pooling no-op -> fused pool)
    k_aggregate<<<aggGrid, 256, 0, stream>>>(Abuf, nodeseg, col2);
    k_gemm_pool<<<gemmGrid, 64, 0, stream>>>(Abuf, Wfrag2, b2_rel, pooled);

    // classifier + log_softmax
    k_final<<<NGRAPH, 64, 0, stream>>>(pooled, W_lin, b_lin, out);
}

// Round 8
// 372.957 us; speedup vs baseline: 1.7185x; 1.0405x over previous
//
#include <hip/hip_runtime.h>

#define N_NODES 51200
#define N_EDGES 819200
#define HDIM 128
#define AK 256          // GEMM K = 2*HDIM (agg | x)
#define NGRAPH 128
#define SEG 400
#define NOUT 10
#define NS 8            // CSR slices (one per XCD via blockIdx%8 heuristic)
#define CSR_M (NS * N_NODES)

typedef unsigned short ushort_t;
typedef __attribute__((ext_vector_type(8))) short bf16x8;
typedef __attribute__((ext_vector_type(16))) float f32x16;

static __device__ __forceinline__ unsigned short f2bf(float f) {
    unsigned int u = __float_as_uint(f);
    unsigned int r = (u + 0x7fffu + ((u >> 16) & 1u)) >> 16;  // RNE
    return (unsigned short)r;
}
static __device__ __forceinline__ float bf2f(unsigned short h) {
    return __uint_as_float(((unsigned int)h) << 16);
}

// ---------------- CSR build (slice-major fill for XCD write locality) ----------------

__global__ void k_count(const int* __restrict__ dst, int* __restrict__ counts) {
    int e = blockIdx.x * 256 + threadIdx.x;
    int s = blockIdx.x & 7;
    atomicAdd(&counts[s * N_NODES + dst[e]], 1);
}

// block = 256 threads, 4 items/thread -> 1024 elements/block; grid = CSR_M/1024 = 400
__global__ void k_scan_block(const int* __restrict__ counts,
                             int* __restrict__ partial,
                             int* __restrict__ blocksums) {
    __shared__ int tsum[256];
    int tid = threadIdx.x;
    int base = blockIdx.x * 1024 + tid * 4;
    int4 c = *(const int4*)(counts + base);
    int s1 = c.x, s2 = s1 + c.y, s3 = s2 + c.z, s4 = s3 + c.w;
    tsum[tid] = s4;
    __syncthreads();
    for (int off = 1; off < 256; off <<= 1) {
        int t = (tid >= off) ? tsum[tid - off] : 0;
        __syncthreads();
        tsum[tid] += t;
        __syncthreads();
    }
    int excl = tsum[tid] - s4;
    int4 o;
    o.x = excl; o.y = excl + s1; o.z = excl + s2; o.w = excl + s3;
    *(int4*)(partial + base) = o;
    if (tid == 255) blocksums[blockIdx.x] = tsum[255];
}

// single block, 512 threads, scans 400 block sums
__global__ void k_scan_top(const int* __restrict__ blocksums, int* __restrict__ blockoffs) {
    __shared__ int s[512];
    int tid = threadIdx.x;
    int v = (tid < 400) ? blocksums[tid] : 0;
    s[tid] = v;
    __syncthreads();
    for (int off = 1; off < 512; off <<= 1) {
        int t = (tid >= off) ? s[tid - off] : 0;
        __syncthreads();
        s[tid] += t;
        __syncthreads();
    }
    if (tid < 400) blockoffs[tid] = s[tid] - v;
}

// fill: rp_sl computed inline from partial+blockoffs
__global__ void k_fill(const int* __restrict__ src, const int* __restrict__ dst,
                       const int* __restrict__ partial, const int* __restrict__ blockoffs,
                       int* __restrict__ cursor, ushort_t* __restrict__ col_sl) {
    int e = blockIdx.x * 256 + threadIdx.x;
    int idx = (blockIdx.x & 7) * N_NODES + dst[e];
    int rp = partial[idx] + blockoffs[idx >> 10];
    int pos = rp + atomicAdd(&cursor[idx], 1);
    col_sl[pos] = (ushort_t)src[e];
}

// regroup: slice-major col -> node-contiguous col2; bases via wave-scanned atomic bump
__global__ __launch_bounds__(256) void k_regroup(const int* __restrict__ counts,
                                                 const int* __restrict__ partial,
                                                 const int* __restrict__ blockoffs,
                                                 const ushort_t* __restrict__ col_sl,
                                                 ushort_t* __restrict__ col2,
                                                 int2* __restrict__ nodeseg,
                                                 int* __restrict__ gtotal) {
    int n = blockIdx.x * 256 + threadIdx.x;
    int lane = threadIdx.x & 63;

    int deg = 0;
#pragma unroll
    for (int s = 0; s < 8; ++s) deg += counts[s * N_NODES + n];

    // wave inclusive scan of deg
    int incl = deg;
#pragma unroll
    for (int off = 1; off < 64; off <<= 1) {
        int t = __shfl_up(incl, off);
        if (lane >= off) incl += t;
    }
    int excl = incl - deg;
    int wtotal = __shfl(incl, 63);
    int wbase = 0;
    if (lane == 0) wbase = atomicAdd(gtotal, wtotal);
    wbase = __shfl(wbase, 0);
    int base = wbase + excl;

    nodeseg[n] = make_int2(base, base + deg);

#pragma unroll
    for (int s = 0; s < 8; ++s) {
        int i = s * N_NODES + n;
        int b = partial[i] + blockoffs[i >> 10];
        int cnt = counts[i];
        for (int e = 0; e < cnt; ++e) col2[base++] = col_sl[b + e];
    }
}

// ---------------- prep: cast x0 -> Abuf right half, build both Wfrags, zero pooled ----

__global__ void k_prep(const float* __restrict__ x, ushort_t* __restrict__ Abuf,
                       const float* __restrict__ W1rel, const float* __restrict__ W1root,
                       const float* __restrict__ W2rel, const float* __restrict__ W2root,
                       ushort_t* __restrict__ Wfrag1, ushort_t* __restrict__ Wfrag2,
                       float* __restrict__ pooled) {
    int b = blockIdx.x;
    if (b < 6400) {
        int idx = b * 256 + threadIdx.x;
        int row = idx >> 5;
        int c4 = (idx & 31) * 4;
        float4 v = *(const float4*)(x + (size_t)row * HDIM + c4);
        ushort4 h;
        h.x = f2bf(v.x); h.y = f2bf(v.y); h.z = f2bf(v.z); h.w = f2bf(v.w);
        *(ushort4*)(Abuf + (size_t)row * AK + HDIM + c4) = h;
    } else if (b < 6656) {
        int w2 = (b >= 6528);
        int tid = (b - (w2 ? 6528 : 6400)) * 256 + threadIdx.x;  // 0..32767
        const float* Wrel  = w2 ? W2rel : W1rel;
        const float* Wroot = w2 ? W2root : W1root;
        ushort_t* dstF     = w2 ? Wfrag2 : Wfrag1;
        int j = tid & 7;
        int l = (tid >> 3) & 63;
        int s = (tid >> 9) & 15;
        int t = tid >> 13;
        int k = 16 * s + (l >> 5) * 8 + j;
        int n = 32 * t + (l & 31);
        float v = (k < HDIM) ? Wrel[(size_t)k * HDIM + n]
                             : Wroot[(size_t)(k - HDIM) * HDIM + n];
        dstF[tid] = f2bf(v);
    } else {
        int i = (b - 6656) * 256 + threadIdx.x;  // 0..16383
        pooled[i] = 0.f;
    }
}

// ---------------- aggregation: half-wave edge pairing, dwordx2 gathers ----------------
// lanes 0-31 gather edge j, lanes 32-63 edge j+1; 8B/lane -> 512B per load instr

__global__ __launch_bounds__(256) void k_aggregate(ushort_t* __restrict__ Abuf,
                                                   const int2* __restrict__ nodeseg,
                                                   const ushort_t* __restrict__ col) {
    int wave = threadIdx.x >> 6;
    int lane = threadIdx.x & 63;
    int il = lane & 31;          // col group: cols 4*il..4*il+3
    int hw = lane >> 5;          // which edge of the pair
    int node = blockIdx.x * 4 + wave;
    int2 se = nodeseg[node];
    int beg = se.x, end = se.y;

    const ushort_t* xsrc = Abuf + HDIM + (size_t)il * 4;

    float a0[8], a1[8], a2[8], a3[8];
#pragma unroll
    for (int j = 0; j < 8; ++j) { a0[j] = 0.f; a1[j] = 0.f; a2[j] = 0.f; a3[j] = 0.f; }

    int e = beg;
    // stage 1: 16 edges per iter (8 pair-slots in flight)
    for (; e + 16 <= end; e += 16) {
        int c[8];
#pragma unroll
        for (int j = 0; j < 8; ++j) c[j] = (int)col[e + 2 * j + hw];
#pragma unroll
        for (int j = 0; j < 8; ++j) {
            ushort4 v = *(const ushort4*)(xsrc + (size_t)c[j] * AK);
            a0[j] += bf2f(v.x); a1[j] += bf2f(v.y);
            a2[j] += bf2f(v.z); a3[j] += bf2f(v.w);
        }
    }
    // stage 2: 8 edges per iter (4 pair-slots)
    for (; e + 8 <= end; e += 8) {
        int c[4];
#pragma unroll
        for (int j = 0; j < 4; ++j) c[j] = (int)col[e + 2 * j + hw];
#pragma unroll
        for (int j = 0; j < 4; ++j) {
            ushort4 v = *(const ushort4*)(xsrc + (size_t)c[j] * AK);
            a0[j] += bf2f(v.x); a1[j] += bf2f(v.y);
            a2[j] += bf2f(v.z); a3[j] += bf2f(v.w);
        }
    }
    // tail: masked pairs
    for (; e < end; e += 2) {
        int idx = e + hw;
        bool ok = idx < end;
        int cc = (int)col[ok ? idx : e];
        ushort4 v = *(const ushort4*)(xsrc + (size_t)cc * AK);
        a0[0] += ok ? bf2f(v.x) : 0.f;
        a1[0] += ok ? bf2f(v.y) : 0.f;
        a2[0] += ok ? bf2f(v.z) : 0.f;
        a3[0] += ok ? bf2f(v.w) : 0.f;
    }

    float s0 = ((a0[0] + a0[1]) + (a0[2] + a0[3])) + ((a0[4] + a0[5]) + (a0[6] + a0[7]));
    float s1 = ((a1[0] + a1[1]) + (a1[2] + a1[3])) + ((a1[4] + a1[5]) + (a1[6] + a1[7]));
    float s2 = ((a2[0] + a2[1]) + (a2[2] + a2[3])) + ((a2[4] + a2[5]) + (a2[6] + a2[7]));
    float s3 = ((a3[0] + a3[1]) + (a3[2] + a3[3])) + ((a3[4] + a3[5]) + (a3[6] + a3[7]));
    // combine the two half-waves
    s0 += __shfl_xor(s0, 32);
    s1 += __shfl_xor(s1, 32);
    s2 += __shfl_xor(s2, 32);
    s3 += __shfl_xor(s3, 32);

    if (hw == 0) {
        ushort4 o;
        o.x = f2bf(s0); o.y = f2bf(s1); o.z = f2bf(s2); o.w = f2bf(s3);
        *(ushort4*)(Abuf + (size_t)node * AK + il * 4) = o;
    }
}

// ---------------- MFMA GEMM (layers 1-2): y = relu([agg|x] @ W + b) -------------

__global__ __launch_bounds__(64) void k_gemm_mfma(const ushort_t* __restrict__ Abuf,
                                                  const ushort_t* __restrict__ Wfrag,
                                                  const float* __restrict__ bias,
                                                  ushort_t* __restrict__ y) {
    __shared__ ushort_t sm[32][136];
    int lane = threadIdx.x;
    int row0 = blockIdx.x * 32;
    int m = lane & 31;
    int half = lane >> 5;

    f32x16 acc[4];
#pragma unroll
    for (int t = 0; t < 4; ++t) acc[t] = (f32x16)(0.f);

    float bb[4];
#pragma unroll
    for (int t = 0; t < 4; ++t) bb[t] = bias[t * 32 + m];

    const ushort_t* arow = Abuf + (size_t)(row0 + m) * AK + half * 8;
    const ushort_t* wf = Wfrag + (size_t)lane * 8;

#pragma unroll
    for (int s = 0; s < 16; ++s) {
        bf16x8 afrag = *(const bf16x8*)(arow + s * 16);
#pragma unroll
        for (int t = 0; t < 4; ++t) {
            bf16x8 bfrag = *(const bf16x8*)(wf + (size_t)(t * 16 + s) * 64 * 8);
            acc[t] = __builtin_amdgcn_mfma_f32_32x32x16_bf16(afrag, bfrag, acc[t], 0, 0, 0);
        }
    }

#pragma unroll
    for (int t = 0; t < 4; ++t) {
#pragma unroll
        for (int r = 0; r < 16; ++r) {
            int rowL = (r & 3) + 8 * (r >> 2) + 4 * half;
            sm[rowL][t * 32 + m] = f2bf(fmaxf(acc[t][r] + bb[t], 0.f));
        }
    }
    __syncthreads();
    int seg = lane & 15;
    int rbase = lane >> 4;
#pragma unroll
    for (int it = 0; it < 8; ++it) {
        int rowL = rbase + it * 4;
        int4 chunk = *(const int4*)&sm[rowL][seg * 8];
        *(int4*)(y + (size_t)(row0 + rowL) * HDIM + seg * 8) = chunk;
    }
}

// ---------------- MFMA GEMM layer-3: relu -> per-graph pooled atomicAdd ----------

__global__ __launch_bounds__(64) void k_gemm_pool(const ushort_t* __restrict__ Abuf,
                                                  const ushort_t* __restrict__ Wfrag,
                                                  const float* __restrict__ bias,
                                                  float* __restrict__ pooled) {
    int lane = threadIdx.x;
    int row0 = blockIdx.x * 32;
    int m = lane & 31;
    int half = lane >> 5;

    f32x16 acc[4];
#pragma unroll
    for (int t = 0; t < 4; ++t) acc[t] = (f32x16)(0.f);

    float bb[4];
#pragma unroll
    for (int t = 0; t < 4; ++t) bb[t] = bias[t * 32 + m];

    const ushort_t* arow = Abuf + (size_t)(row0 + m) * AK + half * 8;
    const ushort_t* wf = Wfrag + (size_t)lane * 8;

#pragma unroll
    for (int s = 0; s < 16; ++s) {
        bf16x8 afrag = *(const bf16x8*)(arow + s * 16);
#pragma unroll
        for (int t = 0; t < 4; ++t) {
            bf16x8 bfrag = *(const bf16x8*)(wf + (size_t)(t * 16 + s) * 64 * 8);
            acc[t] = __builtin_amdgcn_mfma_f32_32x32x16_bf16(afrag, bfrag, acc[t], 0, 0, 0);
        }
    }

    int g0 = row0 / SEG;
    int bnd = (g0 + 1) * SEG;
    int straddle = (row0 + 31 >= bnd);

#pragma unroll
    for (int t = 0; t < 4; ++t) {
        float s0 = 0.f, s1 = 0.f;
#pragma unroll
        for (int r = 0; r < 16; ++r) {
            int row = row0 + (r & 3) + 8 * (r >> 2) + 4 * half;
            float v = fmaxf(acc[t][r] + bb[t], 0.f);
            if (row < bnd) s0 += v; else s1 += v;
        }
        s0 += __shfl_xor(s0, 32);
        s1 += __shfl_xor(s1, 32);
        if (half == 0) {
            atomicAdd(&pooled[g0 * HDIM + t * 32 + m], s0);
            if (straddle) atomicAdd(&pooled[(g0 + 1) * HDIM + t * 32 + m], s1);
        }
    }
}

// ---------------- mixup: bf16 y -> Abuf right half ----------------

__global__ void k_mixup_toA(const ushort_t* __restrict__ y, const int* __restrict__ perm,
                            const float* __restrict__ lam, ushort_t* __restrict__ Abuf) {
    int idx = blockIdx.x * 256 + threadIdx.x;
    int row = idx >> 5;
    int c4 = (idx & 31) * 4;
    float l = lam[0];
    float om = 1.f - l;
    int p = perm[row];
    ushort4 a = *(const ushort4*)(y + (size_t)row * HDIM + c4);
    ushort4 b = *(const ushort4*)(y + (size_t)p * HDIM + c4);
    ushort4 o;
    o.x = f2bf(l * bf2f(a.x) + om * bf2f(b.x));
    o.y = f2bf(l * bf2f(a.y) + om * bf2f(b.y));
    o.z = f2bf(l * bf2f(a.z) + om * bf2f(b.z));
    o.w = f2bf(l * bf2f(a.w) + om * bf2f(b.w));
    *(ushort4*)(Abuf + (size_t)row * AK + HDIM + c4) = o;
}

// ---------------- final: linear + log_softmax from pooled ----------------

__global__ __launch_bounds__(64) void k_final(const float* __restrict__ pooled,
                                              const float* __restrict__ Wlin,
                                              const float* __restrict__ blin,
                                              float* __restrict__ out) {
    int g = blockIdx.x;
    int lane = threadIdx.x;
    float2 v = *(const float2*)(pooled + (size_t)g * HDIM + lane * 2);
    float p[NOUT];
#pragma unroll
    for (int o = 0; o < NOUT; ++o)
        p[o] = v.x * Wlin[(size_t)(2 * lane) * NOUT + o] +
               v.y * Wlin[(size_t)(2 * lane + 1) * NOUT + o];
#pragma unroll
    for (int mask = 1; mask < 64; mask <<= 1)
#pragma unroll
        for (int o = 0; o < NOUT; ++o) p[o] += __shfl_xor(p[o], mask);
    if (lane == 0) {
        float lg[NOUT];
        float mx = -1e30f;
#pragma unroll
        for (int o = 0; o < NOUT; ++o) { lg[o] = p[o] + blin[o]; mx = fmaxf(mx, lg[o]); }
        float se = 0.f;
#pragma unroll
        for (int o = 0; o < NOUT; ++o) se += expf(lg[o] - mx);
        float lse = mx + logf(se);
#pragma unroll
        for (int o = 0; o < NOUT; ++o) out[g * NOUT + o] = lg[o] - lse;
    }
}

// ---------------- host ----------------

extern "C" void kernel_launch(void* const* d_in, const int* in_sizes, int n_in,
                              void* d_out, int out_size, void* d_ws, size_t ws_size,
                              hipStream_t stream) {
    const float* x0     = (const float*)d_in[0];
    const int*   edge   = (const int*)d_in[1];
    const int*   src    = edge;
    const int*   dst    = edge + N_EDGES;
    const float* lam    = (const float*)d_in[2];
    const int*   perm1  = (const int*)d_in[5];
    const int*   perm2  = (const int*)d_in[6];
    const float* W1_rel = (const float*)d_in[8];
    const float* b1_rel = (const float*)d_in[9];
    const float* W1_root= (const float*)d_in[10];
    const float* W2_rel = (const float*)d_in[11];
    const float* b2_rel = (const float*)d_in[12];
    const float* W2_root= (const float*)d_in[13];
    const float* W_lin  = (const float*)d_in[14];
    const float* b_lin  = (const float*)d_in[15];
    float* out = (float*)d_out;

    char* w = (char*)d_ws;
    size_t off = 0;
    auto alloc = [&](size_t bytes) -> void* {
        void* p = w + off;
        off = (off + bytes + 255) & ~(size_t)255;
        return p;
    };
    // counts, cursor, gtotal contiguous -> ONE memset
    int* counts    = (int*)alloc((size_t)CSR_M * 4);
    int* cursor    = (int*)alloc((size_t)CSR_M * 4);
    int* gtotal    = (int*)alloc(256);
    size_t zero_bytes = (size_t)((char*)gtotal - (char*)counts) + 256;
    int* partial   = (int*)alloc((size_t)CSR_M * 4);
    int* blocksums = (int*)alloc(512 * 4);
    int* blockoffs = (int*)alloc(512 * 4);
    ushort_t* col_sl = (ushort_t*)alloc((size_t)N_EDGES * 2);
    ushort_t* col2   = (ushort_t*)alloc((size_t)N_EDGES * 2);
    int2* nodeseg    = (int2*)alloc((size_t)N_NODES * 8);
    ushort_t* Abuf   = (ushort_t*)alloc((size_t)N_NODES * AK * 2);
    ushort_t* ybuf   = (ushort_t*)alloc((size_t)N_NODES * HDIM * 2);
    ushort_t* Wfrag1 = (ushort_t*)alloc(32768 * 2);
    ushort_t* Wfrag2 = (ushort_t*)alloc(32768 * 2);
    float* pooled    = (float*)alloc((size_t)NGRAPH * HDIM * 4);

    hipMemsetAsync(counts, 0, zero_bytes, stream);

    // CSR build: count -> scan -> fill(slice-major) -> regroup(node-contiguous)
    k_count<<<N_EDGES / 256, 256, 0, stream>>>(dst, counts);
    k_scan_block<<<CSR_M / 1024, 256, 0, stream>>>(counts, partial, blocksums);
    k_scan_top<<<1, 512, 0, stream>>>(blocksums, blockoffs);
    k_fill<<<N_EDGES / 256, 256, 0, stream>>>(src, dst, partial, blockoffs, cursor, col_sl);
    k_regroup<<<N_NODES / 256, 256, 0, stream>>>(counts, partial, blockoffs,
                                                 col_sl, col2, nodeseg, gtotal);

    // prep: cast + wfrag1 + wfrag2 + zero pooled (one kernel)
    k_prep<<<6720, 256, 0, stream>>>(x0, Abuf, W1_rel, W1_root, W2_rel, W2_root,
                                     Wfrag1, Wfrag2, pooled);

    const int aggGrid  = N_NODES / 4;
    const int gemmGrid = N_NODES / 32;
    const int elGrid   = (N_NODES * HDIM / 4) / 256;

    // layer 1
    k_aggregate<<<aggGrid, 256, 0, stream>>>(Abuf, nodeseg, col2);
    k_gemm_mfma<<<gemmGrid, 64, 0, stream>>>(Abuf, Wfrag1, b1_rel, ybuf);
    k_mixup_toA<<<elGrid, 256, 0, stream>>>(ybuf, perm1, lam, Abuf);
    // layer 2
    k_aggregate<<<aggGrid, 256, 0, stream>>>(Abuf, nodeseg, col2);
    k_gemm_mfma<<<gemmGrid, 64, 0, stream>>>(Abuf, Wfrag2, b2_rel, ybuf);
    k_mixup_toA<<<elGrid, 256, 0, stream>>>(ybuf, perm2, lam, Abuf);
    // layer 3 (mixup3 is a pooling no-op -> fused pool)
    k_aggregate<<<aggGrid, 256, 0, stream>>>(Abuf, nodeseg, col2);
    k_gemm_pool<<<gemmGrid, 64, 0, stream>>>(Abuf, Wfrag2, b2_rel, pooled);

    // classifier + log_softmax
    k_final<<<NGRAPH, 64, 0, stream>>>(pooled, W_lin, b_lin, out);
}

// Round 9
// 366.816 us; speedup vs baseline: 1.7473x; 1.0167x over previous
//
#include <hip/hip_runtime.h>

#define N_NODES 51200
#define N_EDGES 819200
#define HDIM 128
#define AK 256          // GEMM K = 2*HDIM (agg | x)
#define NGRAPH 128
#define SEG 400
#define NOUT 10
#define NS 8            // CSR slices (one per XCD via blockIdx%8 heuristic)
#define CSR_M (NS * N_NODES)

typedef unsigned short ushort_t;
typedef unsigned int uint_t;
typedef __attribute__((ext_vector_type(8))) short bf16x8;
typedef __attribute__((ext_vector_type(16))) float f32x16;

static __device__ __forceinline__ unsigned short f2bf(float f) {
    unsigned int u = __float_as_uint(f);
    unsigned int r = (u + 0x7fffu + ((u >> 16) & 1u)) >> 16;  // RNE
    return (unsigned short)r;
}
static __device__ __forceinline__ float bf2f(unsigned short h) {
    return __uint_as_float(((unsigned int)h) << 16);
}

// ---------------- CSR build (slice-major fill for XCD write locality) ----------------

__global__ void k_count(const int* __restrict__ dst, int* __restrict__ counts) {
    int e = blockIdx.x * 256 + threadIdx.x;
    int s = blockIdx.x & 7;
    atomicAdd(&counts[s * N_NODES + dst[e]], 1);
}

// block = 256 threads, 4 items/thread -> 1024 elements/block; grid = CSR_M/1024 = 400
__global__ void k_scan_block(const int* __restrict__ counts,
                             int* __restrict__ partial,
                             int* __restrict__ blocksums) {
    __shared__ int tsum[256];
    int tid = threadIdx.x;
    int base = blockIdx.x * 1024 + tid * 4;
    int4 c = *(const int4*)(counts + base);
    int s1 = c.x, s2 = s1 + c.y, s3 = s2 + c.z, s4 = s3 + c.w;
    tsum[tid] = s4;
    __syncthreads();
    for (int off = 1; off < 256; off <<= 1) {
        int t = (tid >= off) ? tsum[tid - off] : 0;
        __syncthreads();
        tsum[tid] += t;
        __syncthreads();
    }
    int excl = tsum[tid] - s4;
    int4 o;
    o.x = excl; o.y = excl + s1; o.z = excl + s2; o.w = excl + s3;
    *(int4*)(partial + base) = o;
    if (tid == 255) blocksums[blockIdx.x] = tsum[255];
}

// single block, 512 threads, scans 400 block sums
__global__ void k_scan_top(const int* __restrict__ blocksums, int* __restrict__ blockoffs) {
    __shared__ int s[512];
    int tid = threadIdx.x;
    int v = (tid < 400) ? blocksums[tid] : 0;
    s[tid] = v;
    __syncthreads();
    for (int off = 1; off < 512; off <<= 1) {
        int t = (tid >= off) ? s[tid - off] : 0;
        __syncthreads();
        s[tid] += t;
        __syncthreads();
    }
    if (tid < 400) blockoffs[tid] = s[tid] - v;
}

// fill: rp_sl computed inline from partial+blockoffs
__global__ void k_fill(const int* __restrict__ src, const int* __restrict__ dst,
                       const int* __restrict__ partial, const int* __restrict__ blockoffs,
                       int* __restrict__ cursor, ushort_t* __restrict__ col_sl) {
    int e = blockIdx.x * 256 + threadIdx.x;
    int idx = (blockIdx.x & 7) * N_NODES + dst[e];
    int rp = partial[idx] + blockoffs[idx >> 10];
    int pos = rp + atomicAdd(&cursor[idx], 1);
    col_sl[pos] = (ushort_t)src[e];
}

// regroup: slice-major col -> node-contiguous col2 (pair-aligned bases, uint writes)
__global__ __launch_bounds__(256) void k_regroup(const int* __restrict__ counts,
                                                 const int* __restrict__ partial,
                                                 const int* __restrict__ blockoffs,
                                                 const ushort_t* __restrict__ col_sl,
                                                 uint_t* __restrict__ col2w,
                                                 int2* __restrict__ nodeseg,
                                                 int* __restrict__ gtotal) {
    int n = blockIdx.x * 256 + threadIdx.x;
    int lane = threadIdx.x & 63;

    int deg = 0;
#pragma unroll
    for (int s = 0; s < 8; ++s) deg += counts[s * N_NODES + n];
    int cap = (deg + 1) & ~1;   // round up to even -> pair-aligned bases

    // wave inclusive scan of cap
    int incl = cap;
#pragma unroll
    for (int off = 1; off < 64; off <<= 1) {
        int t = __shfl_up(incl, off);
        if (lane >= off) incl += t;
    }
    int excl = incl - cap;
    int wtotal = __shfl(incl, 63);
    int wbase = 0;
    if (lane == 0) wbase = atomicAdd(gtotal, wtotal);
    wbase = __shfl(wbase, 0);
    int base = wbase + excl;    // even

    nodeseg[n] = make_int2(base, base + deg);

    int wpos = base >> 1;       // uint index
    uint_t pend = 0;
    int parity = 0;
#pragma unroll
    for (int s = 0; s < 8; ++s) {
        int i = s * N_NODES + n;
        int b = partial[i] + blockoffs[i >> 10];
        int cnt = counts[i];
        for (int e = 0; e < cnt; ++e) {
            uint_t v = (uint_t)col_sl[b + e];
            if (parity == 0) { pend = v; parity = 1; }
            else { col2w[wpos++] = pend | (v << 16); parity = 0; }
        }
    }
    if (parity) col2w[wpos] = pend | (pend << 16);  // pad duplicates last (ignored: end=base+deg)
}

// ---------------- prep: cast x0 -> Abuf right half, build both Wfrags, zero pooled ----

__global__ void k_prep(const float* __restrict__ x, ushort_t* __restrict__ Abuf,
                       const float* __restrict__ W1rel, const float* __restrict__ W1root,
                       const float* __restrict__ W2rel, const float* __restrict__ W2root,
                       ushort_t* __restrict__ Wfrag1, ushort_t* __restrict__ Wfrag2,
                       float* __restrict__ pooled) {
    int b = blockIdx.x;
    if (b < 6400) {
        int idx = b * 256 + threadIdx.x;
        int row = idx >> 5;
        int c4 = (idx & 31) * 4;
        float4 v = *(const float4*)(x + (size_t)row * HDIM + c4);
        ushort4 h;
        h.x = f2bf(v.x); h.y = f2bf(v.y); h.z = f2bf(v.z); h.w = f2bf(v.w);
        *(ushort4*)(Abuf + (size_t)row * AK + HDIM + c4) = h;
    } else if (b < 6656) {
        int w2 = (b >= 6528);
        int tid = (b - (w2 ? 6528 : 6400)) * 256 + threadIdx.x;  // 0..32767
        const float* Wrel  = w2 ? W2rel : W1rel;
        const float* Wroot = w2 ? W2root : W1root;
        ushort_t* dstF     = w2 ? Wfrag2 : Wfrag1;
        int j = tid & 7;
        int l = (tid >> 3) & 63;
        int s = (tid >> 9) & 15;
        int t = tid >> 13;
        int k = 16 * s + (l >> 5) * 8 + j;
        int n = 32 * t + (l & 31);
        float v = (k < HDIM) ? Wrel[(size_t)k * HDIM + n]
                             : Wroot[(size_t)(k - HDIM) * HDIM + n];
        dstF[tid] = f2bf(v);
    } else {
        int i = (b - 6656) * 256 + threadIdx.x;  // 0..16383
        pooled[i] = 0.f;
    }
}

// ---------------- aggregation: half-wave edge pairing, uint2 gathers, min-VALU unpack --

__global__ __launch_bounds__(256) void k_aggregate(ushort_t* __restrict__ Abuf,
                                                   const int2* __restrict__ nodeseg,
                                                   const ushort_t* __restrict__ col) {
    int wave = threadIdx.x >> 6;
    int lane = threadIdx.x & 63;
    int il = lane & 31;          // col group: cols 4*il..4*il+3
    int hw = lane >> 5;          // which edge of the pair
    int node = blockIdx.x * 4 + wave;
    int2 se = nodeseg[node];
    int beg = se.x, end = se.y;

    const ushort_t* xsrc = Abuf + HDIM + (size_t)il * 4;

    float a0[8], a1[8], a2[8], a3[8];
#pragma unroll
    for (int j = 0; j < 8; ++j) { a0[j] = 0.f; a1[j] = 0.f; a2[j] = 0.f; a3[j] = 0.f; }

    int e = beg;
    // stage 1: 16 edges per iter (8 pair-slots in flight)
    for (; e + 16 <= end; e += 16) {
        int c[8];
#pragma unroll
        for (int j = 0; j < 8; ++j) c[j] = (int)col[e + 2 * j + hw];
#pragma unroll
        for (int j = 0; j < 8; ++j) {
            uint2 v = *(const uint2*)(xsrc + (size_t)c[j] * AK);
            a0[j] += __uint_as_float(v.x << 16);
            a1[j] += __uint_as_float(v.x & 0xffff0000u);
            a2[j] += __uint_as_float(v.y << 16);
            a3[j] += __uint_as_float(v.y & 0xffff0000u);
        }
    }
    // stage 2: 8 edges per iter (4 pair-slots)
    for (; e + 8 <= end; e += 8) {
        int c[4];
#pragma unroll
        for (int j = 0; j < 4; ++j) c[j] = (int)col[e + 2 * j + hw];
#pragma unroll
        for (int j = 0; j < 4; ++j) {
            uint2 v = *(const uint2*)(xsrc + (size_t)c[j] * AK);
            a0[j] += __uint_as_float(v.x << 16);
            a1[j] += __uint_as_float(v.x & 0xffff0000u);
            a2[j] += __uint_as_float(v.y << 16);
            a3[j] += __uint_as_float(v.y & 0xffff0000u);
        }
    }
    // tail: masked pairs
    for (; e < end; e += 2) {
        int idx = e + hw;
        bool ok = idx < end;
        int cc = (int)col[ok ? idx : e];
        uint2 v = *(const uint2*)(xsrc + (size_t)cc * AK);
        a0[0] += ok ? __uint_as_float(v.x << 16) : 0.f;
        a1[0] += ok ? __uint_as_float(v.x & 0xffff0000u) : 0.f;
        a2[0] += ok ? __uint_as_float(v.y << 16) : 0.f;
        a3[0] += ok ? __uint_as_float(v.y & 0xffff0000u) : 0.f;
    }

    float s0 = ((a0[0] + a0[1]) + (a0[2] + a0[3])) + ((a0[4] + a0[5]) + (a0[6] + a0[7]));
    float s1 = ((a1[0] + a1[1]) + (a1[2] + a1[3])) + ((a1[4] + a1[5]) + (a1[6] + a1[7]));
    float s2 = ((a2[0] + a2[1]) + (a2[2] + a2[3])) + ((a2[4] + a2[5]) + (a2[6] + a2[7]));
    float s3 = ((a3[0] + a3[1]) + (a3[2] + a3[3])) + ((a3[4] + a3[5]) + (a3[6] + a3[7]));
    s0 += __shfl_xor(s0, 32);
    s1 += __shfl_xor(s1, 32);
    s2 += __shfl_xor(s2, 32);
    s3 += __shfl_xor(s3, 32);

    if (hw == 0) {
        ushort4 o;
        o.x = f2bf(s0); o.y = f2bf(s1); o.z = f2bf(s2); o.w = f2bf(s3);
        *(ushort4*)(Abuf + (size_t)node * AK + il * 4) = o;
    }
}

// ---------------- MFMA GEMM (layers 1-2): split-N, wave = 32 rows x 64 cols ---------

__global__ __launch_bounds__(64) void k_gemm_mfma(const ushort_t* __restrict__ Abuf,
                                                  const ushort_t* __restrict__ Wfrag,
                                                  const float* __restrict__ bias,
                                                  ushort_t* __restrict__ y) {
    __shared__ ushort_t sm[32][72];   // 144 B rows (16B-divisible)
    int lane = threadIdx.x;
    int nh = blockIdx.x & 1;                 // which 64-col half
    int row0 = (blockIdx.x >> 1) * 32;
    int m = lane & 31;
    int half = lane >> 5;

    f32x16 acc[2];
#pragma unroll
    for (int t = 0; t < 2; ++t) acc[t] = (f32x16)(0.f);

    float bb[2];
#pragma unroll
    for (int t = 0; t < 2; ++t) bb[t] = bias[nh * 64 + t * 32 + m];

    const ushort_t* arow = Abuf + (size_t)(row0 + m) * AK + half * 8;
    const ushort_t* wf = Wfrag + (size_t)lane * 8 + (size_t)nh * 2 * 16 * 512;

#pragma unroll
    for (int s = 0; s < 16; ++s) {
        bf16x8 afrag = *(const bf16x8*)(arow + s * 16);
#pragma unroll
        for (int t = 0; t < 2; ++t) {
            bf16x8 bfrag = *(const bf16x8*)(wf + (size_t)(t * 16 + s) * 512);
            acc[t] = __builtin_amdgcn_mfma_f32_32x32x16_bf16(afrag, bfrag, acc[t], 0, 0, 0);
        }
    }

#pragma unroll
    for (int t = 0; t < 2; ++t) {
#pragma unroll
        for (int r = 0; r < 16; ++r) {
            int rowL = (r & 3) + 8 * (r >> 2) + 4 * half;
            sm[rowL][t * 32 + m] = f2bf(fmaxf(acc[t][r] + bb[t], 0.f));
        }
    }
    __syncthreads();
    int seg = lane & 7;          // 8 cols = 16 B
    int rbase = lane >> 3;       // 0..7
#pragma unroll
    for (int it = 0; it < 4; ++it) {
        int rowL = rbase + it * 8;
        int4 chunk = *(const int4*)&sm[rowL][seg * 8];
        *(int4*)(y + (size_t)(row0 + rowL) * HDIM + nh * 64 + seg * 8) = chunk;
    }
}

// ---------------- MFMA GEMM layer-3: split-N, relu -> per-graph pooled atomicAdd -----

__global__ __launch_bounds__(64) void k_gemm_pool(const ushort_t* __restrict__ Abuf,
                                                  const ushort_t* __restrict__ Wfrag,
                                                  const float* __restrict__ bias,
                                                  float* __restrict__ pooled) {
    int lane = threadIdx.x;
    int nh = blockIdx.x & 1;
    int row0 = (blockIdx.x >> 1) * 32;
    int m = lane & 31;
    int half = lane >> 5;

    f32x16 acc[2];
#pragma unroll
    for (int t = 0; t < 2; ++t) acc[t] = (f32x16)(0.f);

    float bb[2];
#pragma unroll
    for (int t = 0; t < 2; ++t) bb[t] = bias[nh * 64 + t * 32 + m];

    const ushort_t* arow = Abuf + (size_t)(row0 + m) * AK + half * 8;
    const ushort_t* wf = Wfrag + (size_t)lane * 8 + (size_t)nh * 2 * 16 * 512;

#pragma unroll
    for (int s = 0; s < 16; ++s) {
        bf16x8 afrag = *(const bf16x8*)(arow + s * 16);
#pragma unroll
        for (int t = 0; t < 2; ++t) {
            bf16x8 bfrag = *(const bf16x8*)(wf + (size_t)(t * 16 + s) * 512);
            acc[t] = __builtin_amdgcn_mfma_f32_32x32x16_bf16(afrag, bfrag, acc[t], 0, 0, 0);
        }
    }

    int g0 = row0 / SEG;
    int bnd = (g0 + 1) * SEG;
    int straddle = (row0 + 31 >= bnd);

#pragma unroll
    for (int t = 0; t < 2; ++t) {
        float s0 = 0.f, s1 = 0.f;
#pragma unroll
        for (int r = 0; r < 16; ++r) {
            int row = row0 + (r & 3) + 8 * (r >> 2) + 4 * half;
            float v = fmaxf(acc[t][r] + bb[t], 0.f);
            if (row < bnd) s0 += v; else s1 += v;
        }
        s0 += __shfl_xor(s0, 32);
        s1 += __shfl_xor(s1, 32);
        if (half == 0) {
            int coln = nh * 64 + t * 32 + m;
            atomicAdd(&pooled[g0 * HDIM + coln], s0);
            if (straddle) atomicAdd(&pooled[(g0 + 1) * HDIM + coln], s1);
        }
    }
}

// ---------------- mixup: bf16 y -> Abuf right half ----------------

__global__ void k_mixup_toA(const ushort_t* __restrict__ y, const int* __restrict__ perm,
                            const float* __restrict__ lam, ushort_t* __restrict__ Abuf) {
    int idx = blockIdx.x * 256 + threadIdx.x;
    int row = idx >> 5;
    int c4 = (idx & 31) * 4;
    float l = lam[0];
    float om = 1.f - l;
    int p = perm[row];
    ushort4 a = *(const ushort4*)(y + (size_t)row * HDIM + c4);
    ushort4 b = *(const ushort4*)(y + (size_t)p * HDIM + c4);
    ushort4 o;
    o.x = f2bf(l * bf2f(a.x) + om * bf2f(b.x));
    o.y = f2bf(l * bf2f(a.y) + om * bf2f(b.y));
    o.z = f2bf(l * bf2f(a.z) + om * bf2f(b.z));
    o.w = f2bf(l * bf2f(a.w) + om * bf2f(b.w));
    *(ushort4*)(Abuf + (size_t)row * AK + HDIM + c4) = o;
}

// ---------------- final: linear + log_softmax from pooled ----------------

__global__ __launch_bounds__(64) void k_final(const float* __restrict__ pooled,
                                              const float* __restrict__ Wlin,
                                              const float* __restrict__ blin,
                                              float* __restrict__ out) {
    int g = blockIdx.x;
    int lane = threadIdx.x;
    float2 v = *(const float2*)(pooled + (size_t)g * HDIM + lane * 2);
    float p[NOUT];
#pragma unroll
    for (int o = 0; o < NOUT; ++o)
        p[o] = v.x * Wlin[(size_t)(2 * lane) * NOUT + o] +
               v.y * Wlin[(size_t)(2 * lane + 1) * NOUT + o];
#pragma unroll
    for (int mask = 1; mask < 64; mask <<= 1)
#pragma unroll
        for (int o = 0; o < NOUT; ++o) p[o] += __shfl_xor(p[o], mask);
    if (lane == 0) {
        float lg[NOUT];
        float mx = -1e30f;
#pragma unroll
        for (int o = 0; o < NOUT; ++o) { lg[o] = p[o] + blin[o]; mx = fmaxf(mx, lg[o]); }
        float se = 0.f;
#pragma unroll
        for (int o = 0; o < NOUT; ++o) se += expf(lg[o] - mx);
        float lse = mx + logf(se);
#pragma unroll
        for (int o = 0; o < NOUT; ++o) out[g * NOUT + o] = lg[o] - lse;
    }
}

// ---------------- host ----------------

extern "C" void kernel_launch(void* const* d_in, const int* in_sizes, int n_in,
                              void* d_out, int out_size, void* d_ws, size_t ws_size,
                              hipStream_t stream) {
    const float* x0     = (const float*)d_in[0];
    const int*   edge   = (const int*)d_in[1];
    const int*   src    = edge;
    const int*   dst    = edge + N_EDGES;
    const float* lam    = (const float*)d_in[2];
    const int*   perm1  = (const int*)d_in[5];
    const int*   perm2  = (const int*)d_in[6];
    const float* W1_rel = (const float*)d_in[8];
    const float* b1_rel = (const float*)d_in[9];
    const float* W1_root= (const float*)d_in[10];
    const float* W2_rel = (const float*)d_in[11];
    const float* b2_rel = (const float*)d_in[12];
    const float* W2_root= (const float*)d_in[13];
    const float* W_lin  = (const float*)d_in[14];
    const float* b_lin  = (const float*)d_in[15];
    float* out = (float*)d_out;

    char* w = (char*)d_ws;
    size_t off = 0;
    auto alloc = [&](size_t bytes) -> void* {
        void* p = w + off;
        off = (off + bytes + 255) & ~(size_t)255;
        return p;
    };
    // counts, cursor, gtotal contiguous -> ONE memset
    int* counts    = (int*)alloc((size_t)CSR_M * 4);
    int* cursor    = (int*)alloc((size_t)CSR_M * 4);
    int* gtotal    = (int*)alloc(256);
    size_t zero_bytes = (size_t)((char*)gtotal - (char*)counts) + 256;
    int* partial   = (int*)alloc((size_t)CSR_M * 4);
    int* blocksums = (int*)alloc(512 * 4);
    int* blockoffs = (int*)alloc(512 * 4);
    ushort_t* col_sl = (ushort_t*)alloc((size_t)N_EDGES * 2);
    ushort_t* col2   = (ushort_t*)alloc((size_t)(N_EDGES + N_NODES * 2) * 2);  // + pad room
    int2* nodeseg    = (int2*)alloc((size_t)N_NODES * 8);
    ushort_t* Abuf   = (ushort_t*)alloc((size_t)N_NODES * AK * 2);
    ushort_t* ybuf   = (ushort_t*)alloc((size_t)N_NODES * HDIM * 2);
    ushort_t* Wfrag1 = (ushort_t*)alloc(32768 * 2);
    ushort_t* Wfrag2 = (ushort_t*)alloc(32768 * 2);
    float* pooled    = (float*)alloc((size_t)NGRAPH * HDIM * 4);

    hipMemsetAsync(counts, 0, zero_bytes, stream);

    // CSR build: count -> scan -> fill(slice-major) -> regroup(node-contiguous)
    k_count<<<N_EDGES / 256, 256, 0, stream>>>(dst, counts);
    k_scan_block<<<CSR_M / 1024, 256, 0, stream>>>(counts, partial, blocksums);
    k_scan_top<<<1, 512, 0, stream>>>(blocksums, blockoffs);
    k_fill<<<N_EDGES / 256, 256, 0, stream>>>(src, dst, partial, blockoffs, cursor, col_sl);
    k_regroup<<<N_NODES / 256, 256, 0, stream>>>(counts, partial, blockoffs,
                                                 col_sl, (uint_t*)col2, nodeseg, gtotal);

    // prep: cast + wfrag1 + wfrag2 + zero pooled (one kernel)
    k_prep<<<6720, 256, 0, stream>>>(x0, Abuf, W1_rel, W1_root, W2_rel, W2_root,
                                     Wfrag1, Wfrag2, pooled);

    const int aggGrid  = N_NODES / 4;
    const int gemmGrid = (N_NODES / 32) * 2;     // split-N: 2 blocks per 32-row tile
    const int elGrid   = (N_NODES * HDIM / 4) / 256;

    // layer 1
    k_aggregate<<<aggGrid, 256, 0, stream>>>(Abuf, nodeseg, col2);
    k_gemm_mfma<<<gemmGrid, 64, 0, stream>>>(Abuf, Wfrag1, b1_rel, ybuf);
    k_mixup_toA<<<elGrid, 256, 0, stream>>>(ybuf, perm1, lam, Abuf);
    // layer 2
    k_aggregate<<<aggGrid, 256, 0, stream>>>(Abuf, nodeseg, col2);
    k_gemm_mfma<<<gemmGrid, 64, 0, stream>>>(Abuf, Wfrag2, b2_rel, ybuf);
    k_mixup_toA<<<elGrid, 256, 0, stream>>>(ybuf, perm2, lam, Abuf);
    // layer 3 (mixup3 is a pooling no-op -> fused pool)
    k_aggregate<<<aggGrid, 256, 0, stream>>>(Abuf, nodeseg, col2);
    k_gemm_pool<<<gemmGrid, 64, 0, stream>>>(Abuf, Wfrag2, b2_rel, pooled);

    // classifier + log_softmax
    k_final<<<NGRAPH, 64, 0, stream>>>(pooled, W_lin, b_lin, out);
}